// Round 13
// baseline (2027.840 us; speedup 1.0000x reference)
//
#include <hip/hip_runtime.h>
#include <hip/hip_bf16.h>

#define TPB 256
#define CDIV(a,b) (((a)+(b)-1)/(b))

__device__ __forceinline__ float elu_f(float v) {
    return v > 0.f ? v : expm1f(v);
}

__device__ __forceinline__ int ld_idx(const void* __restrict__ ei, int pos, int is64) {
    if (is64) return (int)((const long long*)ei)[pos];
    return ((const int*)ei)[pos];
}

__device__ __forceinline__ void spline_basis(const float* __restrict__ pseudo, int e,
                                             float bas[8], int kidx[8]) {
    float f[3]; int lo[3];
#pragma unroll
    for (int d = 0; d < 3; ++d) {
        float v = pseudo[e * 3 + d] * 4.f;
        float l = floorf(v);
        l = fminf(fmaxf(l, 0.f), 3.f);
        f[d] = v - l;
        lo[d] = (int)l;
    }
#pragma unroll
    for (int s = 0; s < 8; ++s) {
        int b0 = s & 1, b1 = (s >> 1) & 1, b2 = (s >> 2) & 1;
        bas[s] = (b0 ? f[0] : 1.f - f[0]) * (b1 ? f[1] : 1.f - f[1]) * (b2 ? f[2] : 1.f - f[2]);
        kidx[s] = (lo[0] + b0) + 5 * (lo[1] + b1) + 25 * (lo[2] + b2);
    }
}

__global__ void k_detect(const int* __restrict__ ei0_as_i32, int* __restrict__ flag) {
    if (threadIdx.x == 0 && blockIdx.x == 0) {
        int zeros = 0;
        for (int k = 0; k < 128; ++k)
            if (ei0_as_i32[2 * k + 1] == 0) zeros++;
        flag[0] = (zeros >= 120) ? 1 : 0;
    }
}

__global__ __launch_bounds__(TPB) void k_zero(float* __restrict__ p, int n) {
    int t = blockIdx.x * blockDim.x + threadIdx.x;
    if (t < n) p[t] = 0.f;
}

__global__ __launch_bounds__(TPB) void k_zero_i(int* __restrict__ p, int n) {
    int t = blockIdx.x * blockDim.x + threadIdx.x;
    if (t < n) p[t] = 0;
}

// =========== multi-level CSR (levels 0..4) ===========
// node offsets {0,65536,81920,86016,87040} total 87296
// row offsets  {0,65537,81922,86019,87044} total 87301
// eid offsets  {0,393216,491520,516096,522240} total 523776
__global__ __launch_bounds__(TPB) void k_csr_count5(const void* e0, const void* e1,
                                                    const void* e2, const void* e3,
                                                    const void* e4, int* __restrict__ cnt,
                                                    const int* __restrict__ flag) {
    int t = blockIdx.x * blockDim.x + threadIdx.x;
    if (t >= 523776) return;
    int is64 = flag[0];
    const void* ei; int e, E, noff;
    if (t < 393216)      { ei = e0; e = t;          E = 393216; noff = 0; }
    else if (t < 491520) { ei = e1; e = t - 393216; E = 98304;  noff = 65536; }
    else if (t < 516096) { ei = e2; e = t - 491520; E = 24576;  noff = 81920; }
    else if (t < 522240) { ei = e3; e = t - 516096; E = 6144;   noff = 86016; }
    else                 { ei = e4; e = t - 522240; E = 1536;   noff = 87040; }
    int dst = ld_idx(ei, E + e, is64);
    atomicAdd(&cnt[noff + dst], 1);
}

__global__ __launch_bounds__(1024) void k_csr_scan5(const int* __restrict__ cnt,
                                                    int* __restrict__ rows) {
    const int NODES[5] = {65536, 16384, 4096, 1024, 256};
    const int NOFF[5]  = {0, 65536, 81920, 86016, 87040};
    const int ROFF[5]  = {0, 65537, 81922, 86019, 87044};
    int l = blockIdx.x;
    int nodes = NODES[l];
    const int* c = cnt + NOFF[l];
    int* rp = rows + ROFF[l];
    __shared__ int s_part[1024];
    int t = threadIdx.x;
    int chunk = (nodes + 1023) >> 10;
    int b0 = t * chunk;
    int b1 = min(b0 + chunk, nodes);
    int sum = 0;
    for (int i = b0; i < b1; ++i) sum += c[i];
    s_part[t] = sum;
    __syncthreads();
    for (int off = 1; off < 1024; off <<= 1) {
        int v = (t >= off) ? s_part[t - off] : 0;
        __syncthreads();
        s_part[t] += v;
        __syncthreads();
    }
    int run = (t == 0) ? 0 : s_part[t - 1];
    for (int i = b0; i < b1; ++i) { rp[i] = run; run += c[i]; }
    if (t == 0) rp[nodes] = s_part[1023];
}

__global__ __launch_bounds__(TPB) void k_csr_fill5(const void* e0, const void* e1,
                                                   const void* e2, const void* e3,
                                                   const void* e4,
                                                   const int* __restrict__ rows,
                                                   int* __restrict__ cur,
                                                   int* __restrict__ eids,
                                                   const int* __restrict__ flag) {
    int t = blockIdx.x * blockDim.x + threadIdx.x;
    if (t >= 523776) return;
    int is64 = flag[0];
    const void* ei; int e, E, noff, roff, eoff;
    if (t < 393216)      { ei = e0; e = t;          E = 393216; noff = 0;     roff = 0;     eoff = 0; }
    else if (t < 491520) { ei = e1; e = t - 393216; E = 98304;  noff = 65536; roff = 65537; eoff = 393216; }
    else if (t < 516096) { ei = e2; e = t - 491520; E = 24576;  noff = 81920; roff = 81922; eoff = 491520; }
    else if (t < 522240) { ei = e3; e = t - 516096; E = 6144;   noff = 86016; roff = 86019; eoff = 516096; }
    else                 { ei = e4; e = t - 522240; E = 1536;   noff = 87040; roff = 87044; eoff = 522240; }
    int dst = ld_idx(ei, E + e, is64);
    int pos = rows[roff + dst] + atomicAdd(&cur[noff + dst], 1);
    eids[eoff + pos] = e;
}

// single-level CSR (fallback path, ei0 only)
__global__ __launch_bounds__(TPB) void k_csr_count(const void* __restrict__ ei,
                                                   int* __restrict__ cnt, int E,
                                                   const int* __restrict__ flag) {
    int t = blockIdx.x * blockDim.x + threadIdx.x;
    if (t >= E) return;
    int dst = ld_idx(ei, E + t, flag[0]);
    atomicAdd(&cnt[dst], 1);
}

__global__ __launch_bounds__(1024) void k_csr_scan(const int* __restrict__ cnt,
                                                   int* __restrict__ row_ptr) {
    __shared__ int s_part[1024];
    int t = threadIdx.x;
    int base = t * 64;
    int sum = 0;
    for (int i = 0; i < 64; ++i) sum += cnt[base + i];
    s_part[t] = sum;
    __syncthreads();
    for (int off = 1; off < 1024; off <<= 1) {
        int v = (t >= off) ? s_part[t - off] : 0;
        __syncthreads();
        s_part[t] += v;
        __syncthreads();
    }
    int run = (t == 0) ? 0 : s_part[t - 1];
    for (int i = 0; i < 64; ++i) { row_ptr[base + i] = run; run += cnt[base + i]; }
    if (t == 1023) row_ptr[65536] = run;
}

__global__ __launch_bounds__(TPB) void k_csr_fill(const void* __restrict__ ei,
                                                  const int* __restrict__ row_ptr,
                                                  int* __restrict__ cur,
                                                  int* __restrict__ eid, int E,
                                                  const int* __restrict__ flag) {
    int t = blockIdx.x * blockDim.x + threadIdx.x;
    if (t >= E) return;
    int dst = ld_idx(ei, E + t, flag[0]);
    int pos = row_ptr[dst] + atomicAdd(&cur[dst], 1);
    eid[pos] = t;
}

// ---------- c1 gather ----------
__global__ __launch_bounds__(256) void k_gather_c1(const float* __restrict__ x,
                                                   const float* __restrict__ pseudo,
                                                   const void* __restrict__ ei,
                                                   const float* __restrict__ W,
                                                   const float* __restrict__ root,
                                                   const float* __restrict__ bias,
                                                   const int* __restrict__ row_ptr,
                                                   const int* __restrict__ eid,
                                                   float* __restrict__ agg,
                                                   const int* __restrict__ flag) {
    __shared__ float4 s_w[500];
    for (int i = threadIdx.x; i < 500; i += 256)
        s_w[i] = reinterpret_cast<const float4*>(W)[i];
    __syncthreads();
    int t = blockIdx.x * 256 + threadIdx.x;
    int n = t >> 2, cg = t & 3, co0 = cg * 4;
    int is64 = flag[0];
    float xn = x[n];
    float a0 = fmaf(xn, root[co0 + 0], bias[co0 + 0]);
    float a1 = fmaf(xn, root[co0 + 1], bias[co0 + 1]);
    float a2 = fmaf(xn, root[co0 + 2], bias[co0 + 2]);
    float a3 = fmaf(xn, root[co0 + 3], bias[co0 + 3]);
    int rb = row_ptr[n], re = row_ptr[n + 1];
    for (int idx = rb; idx < re; ++idx) {
        int e = eid[idx];
        int src = ld_idx(ei, e, is64);
        float bas[8]; int kidx[8];
        spline_basis(pseudo, e, bas, kidx);
        float xs = x[src];
        float m0 = 0.f, m1 = 0.f, m2 = 0.f, m3 = 0.f;
#pragma unroll
        for (int s = 0; s < 8; ++s) {
            float4 w = s_w[kidx[s] * 4 + cg];
            float bs = bas[s];
            m0 = fmaf(bs, w.x, m0);
            m1 = fmaf(bs, w.y, m1);
            m2 = fmaf(bs, w.z, m2);
            m3 = fmaf(bs, w.w, m3);
        }
        a0 = fmaf(xs, m0, a0);
        a1 = fmaf(xs, m1, a1);
        a2 = fmaf(xs, m2, a2);
        a3 = fmaf(xs, m3, a3);
    }
    float4 v = make_float4(a0, a1, a2, a3);
    *reinterpret_cast<float4*>(&agg[n * 16 + co0]) = v;
}

// ---------- d1 gather ----------
__global__ __launch_bounds__(256) void k_gather_d1(const float* __restrict__ xin,
                                                   const float* __restrict__ pseudo,
                                                   const void* __restrict__ ei,
                                                   const float* __restrict__ W,
                                                   const float* __restrict__ root,
                                                   const float* __restrict__ bias,
                                                   const int* __restrict__ row_ptr,
                                                   const int* __restrict__ eid,
                                                   float* __restrict__ outp,
                                                   const int* __restrict__ flag) {
    __shared__ float s_w[2000];
    for (int i = threadIdx.x; i < 2000; i += 256) s_w[i] = W[i];
    __syncthreads();
    int t = blockIdx.x * 256 + threadIdx.x;
    int n = t >> 2, l = t & 3;
    int is64 = flag[0];
    int rb = row_ptr[n], re = row_ptr[n + 1];
    float acc = 0.f;
    for (int idx = rb + l; idx < re; idx += 4) {
        int e = eid[idx];
        int src = ld_idx(ei, e, is64);
        float bas[8]; int kidx[8];
        spline_basis(pseudo, e, bas, kidx);
        const float4* xs4 = reinterpret_cast<const float4*>(xin + src * 16);
        float4 xv0 = xs4[0], xv1 = xs4[1], xv2 = xs4[2], xv3 = xs4[3];
        float m = 0.f;
#pragma unroll
        for (int s = 0; s < 8; ++s) {
            const float4* wp = reinterpret_cast<const float4*>(s_w + kidx[s] * 16);
            float4 w0 = wp[0], w1 = wp[1], w2 = wp[2], w3 = wp[3];
            float p = 0.f;
            p = fmaf(xv0.x, w0.x, p); p = fmaf(xv0.y, w0.y, p);
            p = fmaf(xv0.z, w0.z, p); p = fmaf(xv0.w, w0.w, p);
            p = fmaf(xv1.x, w1.x, p); p = fmaf(xv1.y, w1.y, p);
            p = fmaf(xv1.z, w1.z, p); p = fmaf(xv1.w, w1.w, p);
            p = fmaf(xv2.x, w2.x, p); p = fmaf(xv2.y, w2.y, p);
            p = fmaf(xv2.z, w2.z, p); p = fmaf(xv2.w, w2.w, p);
            p = fmaf(xv3.x, w3.x, p); p = fmaf(xv3.y, w3.y, p);
            p = fmaf(xv3.z, w3.z, p); p = fmaf(xv3.w, w3.w, p);
            m = fmaf(bas[s], p, m);
        }
        acc += m;
    }
    acc += __shfl_xor(acc, 1);
    acc += __shfl_xor(acc, 2);
    if (l == 0) {
        const float4* xr = reinterpret_cast<const float4*>(xin + n * 16);
        const float4* rr = reinterpret_cast<const float4*>(root);
        float r = bias[0];
#pragma unroll
        for (int q = 0; q < 4; ++q) {
            float4 xv = xr[q], rv = rr[q];
            r = fmaf(xv.x, rv.x, r); r = fmaf(xv.y, rv.y, r);
            r = fmaf(xv.z, rv.z, r); r = fmaf(xv.w, rv.w, r);
        }
        outp[n] = elu_f(r + acc);
    }
}

// ---------- mid-level CSR gather with LDS-staged W slice ----------
// block = (256 nodes, cg, cih); W slice [125][CPT] float4 for (cg,cih) in LDS.
template <int CIN, int COUT, int CSPLIT, int IROOT>
__global__ __launch_bounds__(256) void k_gW(const float* __restrict__ x,
                                            const float* __restrict__ pseudo,
                                            const void* __restrict__ ei,
                                            const float* __restrict__ W,
                                            const float* __restrict__ root,
                                            const float* __restrict__ bias,
                                            const int* __restrict__ row_ptr,
                                            const int* __restrict__ eid,
                                            float* __restrict__ agg,
                                            const int* __restrict__ flag) {
    constexpr int COG = COUT / 4;
    constexpr int CPT = CIN / CSPLIT;
    __shared__ float4 s_w[125 * CPT];
    int cg = blockIdx.y, cih = blockIdx.z;
    const float4* W4 = reinterpret_cast<const float4*>(W);
    for (int i = threadIdx.x; i < 125 * CPT; i += 256) {
        int k = i / CPT, ci = i - k * CPT;
        s_w[i] = W4[(k * CIN + cih * CPT + ci) * COG + cg];
    }
    __syncthreads();
    int n = blockIdx.x * 256 + threadIdx.x;
    int is64 = flag[0];
    int co0 = cg * 4;
    float4 acc = make_float4(0.f, 0.f, 0.f, 0.f);
    if (IROOT) {
        acc = reinterpret_cast<const float4*>(bias)[cg];
        const float* xp = x + (size_t)n * CIN;
        const float4* r4 = reinterpret_cast<const float4*>(root);
#pragma unroll
        for (int ci = 0; ci < CIN; ++ci) {
            float xv = xp[ci];
            float4 rv = r4[ci * COG + cg];
            acc.x = fmaf(xv, rv.x, acc.x); acc.y = fmaf(xv, rv.y, acc.y);
            acc.z = fmaf(xv, rv.z, acc.z); acc.w = fmaf(xv, rv.w, acc.w);
        }
    }
    int rb = row_ptr[n], re = row_ptr[n + 1];
    for (int idx = rb; idx < re; ++idx) {
        int e = eid[idx];
        int src = ld_idx(ei, e, is64);
        float bas[8]; int kidx[8];
        spline_basis(pseudo, e, bas, kidx);
        float xv[CPT];
        const float* xp = x + (size_t)src * CIN + cih * CPT;
#pragma unroll
        for (int ci = 0; ci < CPT; ++ci) xv[ci] = xp[ci];
#pragma unroll
        for (int s = 0; s < 8; ++s) {
            const float4* wp = s_w + kidx[s] * CPT;
            float bs = bas[s];
#pragma unroll
            for (int ci = 0; ci < CPT; ++ci) {
                float bx = bs * xv[ci];
                float4 w = wp[ci];
                acc.x = fmaf(bx, w.x, acc.x); acc.y = fmaf(bx, w.y, acc.y);
                acc.z = fmaf(bx, w.z, acc.z); acc.w = fmaf(bx, w.w, acc.w);
            }
        }
    }
    float* o = agg + (size_t)n * COUT + co0;
    if (IROOT) {
        *reinterpret_cast<float4*>(o) = acc;
    } else {
        atomicAdd(o + 0, acc.x); atomicAdd(o + 1, acc.y);
        atomicAdd(o + 2, acc.z); atomicAdd(o + 3, acc.w);
    }
}

// root transform, cin%4==0
__global__ __launch_bounds__(TPB) void k_root4(const float* __restrict__ x,
                                               const float* __restrict__ root,
                                               const float* __restrict__ bias,
                                               float* __restrict__ out,
                                               int nnode, int cin, int cout) {
    int t = blockIdx.x * blockDim.x + threadIdx.x;
    if (t >= nnode * cout) return;
    int n = t / cout, co = t - n * cout;
    const float4* xr = reinterpret_cast<const float4*>(x + n * cin);
    float a0 = 0.f, a1 = 0.f, a2 = 0.f, a3 = 0.f;
    int q4 = cin >> 2;
    for (int q = 0; q < q4; ++q) {
        float4 xv = xr[q];
        const float* rp = root + (q * 4) * cout + co;
        a0 = fmaf(xv.x, rp[0], a0);
        a1 = fmaf(xv.y, rp[cout], a1);
        a2 = fmaf(xv.z, rp[2 * cout], a2);
        a3 = fmaf(xv.w, rp[3 * cout], a3);
    }
    out[t] = bias[co] + ((a0 + a1) + (a2 + a3));
}

// ---------- generic spline message (atomic scatter) — fallback ----------
template <int CIN, int COUT, int CSPLIT>
__global__ __launch_bounds__(TPB) void k_msg4(const float* __restrict__ x,
                                              const float* __restrict__ pseudo,
                                              const void* __restrict__ ei,
                                              const float* __restrict__ W,
                                              float* __restrict__ agg, int E,
                                              const int* __restrict__ flag) {
    constexpr int COG = COUT / 4;
    constexpr int CPT = CIN / CSPLIT;
    int t = blockIdx.x * blockDim.x + threadIdx.x;
    if (t >= E * COG * CSPLIT) return;
    int is64 = flag[0];
    int cog = t % COG;
    int rest = t / COG;
    int cs = rest % CSPLIT;
    int e = rest / CSPLIT;
    int co0 = cog * 4;
    int src = ld_idx(ei, e, is64);
    int dst = ld_idx(ei, E + e, is64);
    float bas[8]; int kidx[8];
    spline_basis(pseudo, e, bas, kidx);
    int wof[8];
#pragma unroll
    for (int s = 0; s < 8; ++s) wof[s] = kidx[s] * CIN * COUT + co0;
    float a0 = 0.f, a1 = 0.f, a2 = 0.f, a3 = 0.f;
    const float* xp = x + src * CIN + cs * CPT;
    const int cbase = cs * CPT * COUT;
    for (int ci = 0; ci < CPT; ++ci) {
        float xv = xp[ci];
        int off = cbase + ci * COUT;
#pragma unroll
        for (int s = 0; s < 8; ++s) {
            float4 w = *reinterpret_cast<const float4*>(&W[wof[s] + off]);
            float bx = bas[s] * xv;
            a0 = fmaf(bx, w.x, a0);
            a1 = fmaf(bx, w.y, a1);
            a2 = fmaf(bx, w.z, a2);
            a3 = fmaf(bx, w.w, a3);
        }
    }
    float* ap = &agg[dst * COUT + co0];
    atomicAdd(ap + 0, a0);
    atomicAdd(ap + 1, a1);
    atomicAdd(ap + 2, a2);
    atomicAdd(ap + 3, a3);
}

template <int CIN, int COUT>
__global__ __launch_bounds__(TPB) void k_msg_s(const float* __restrict__ x,
                                               const float* __restrict__ pseudo,
                                               const void* __restrict__ ei,
                                               const float* __restrict__ W,
                                               float* __restrict__ agg, int E,
                                               const int* __restrict__ flag) {
    int t = blockIdx.x * blockDim.x + threadIdx.x;
    if (t >= E * COUT) return;
    int is64 = flag[0];
    int e = t / COUT, co = t - e * COUT;
    int src = ld_idx(ei, e, is64);
    int dst = ld_idx(ei, E + e, is64);
    float bas[8]; int kidx[8];
    spline_basis(pseudo, e, bas, kidx);
    float acc = 0.f;
    const float* xp = x + src * CIN;
    for (int ci = 0; ci < CIN; ++ci) {
        float xv = xp[ci];
#pragma unroll
        for (int s = 0; s < 8; ++s)
            acc = fmaf(bas[s] * xv, W[kidx[s] * CIN * COUT + ci * COUT + co], acc);
    }
    atomicAdd(&agg[dst * COUT + co], acc);
}

// c1 fallback (LDS accumulate)
__global__ __launch_bounds__(1024) void k_msg_c1(const float* __restrict__ x,
                                                 const float* __restrict__ pseudo,
                                                 const void* __restrict__ ei,
                                                 const float* __restrict__ W,
                                                 const float* __restrict__ root,
                                                 const float* __restrict__ bias,
                                                 float* __restrict__ agg,
                                                 const int* __restrict__ flag) {
    __shared__ float s_acc[4096 * 4];
    __shared__ float s_w[125 * 4];
    int b = blockIdx.x, cg = blockIdx.y, t = threadIdx.x;
    int co0 = cg * 4;
    int is64 = flag[0];
    if (t < 500) s_w[t] = W[(t >> 2) * 16 + co0 + (t & 3)];
    float r0 = root[co0], r1 = root[co0 + 1], r2 = root[co0 + 2], r3 = root[co0 + 3];
    float b0 = bias[co0], b1 = bias[co0 + 1], b2 = bias[co0 + 2], b3 = bias[co0 + 3];
    for (int n = t; n < 4096; n += 1024) {
        float xv = x[b * 4096 + n];
        s_acc[n * 4 + 0] = fmaf(xv, r0, b0);
        s_acc[n * 4 + 1] = fmaf(xv, r1, b1);
        s_acc[n * 4 + 2] = fmaf(xv, r2, b2);
        s_acc[n * 4 + 3] = fmaf(xv, r3, b3);
    }
    __syncthreads();
    int ebeg = b * 24576;
    for (int k = t; k < 24576; k += 1024) {
        int e = ebeg + k;
        int src = ld_idx(ei, e, is64);
        int dst = ld_idx(ei, 393216 + e, is64);
        float xv = x[src];
        float bas[8]; int kidx[8];
        spline_basis(pseudo, e, bas, kidx);
        float m0 = 0.f, m1 = 0.f, m2 = 0.f, m3 = 0.f;
#pragma unroll
        for (int s = 0; s < 8; ++s) {
            const float* wp = s_w + kidx[s] * 4;
            float bs = bas[s];
            m0 = fmaf(bs, wp[0], m0);
            m1 = fmaf(bs, wp[1], m1);
            m2 = fmaf(bs, wp[2], m2);
            m3 = fmaf(bs, wp[3], m3);
        }
        int dl = (dst - b * 4096) * 4;
        atomicAdd(&s_acc[dl + 0], m0 * xv);
        atomicAdd(&s_acc[dl + 1], m1 * xv);
        atomicAdd(&s_acc[dl + 2], m2 * xv);
        atomicAdd(&s_acc[dl + 3], m3 * xv);
    }
    __syncthreads();
    for (int n = t; n < 4096; n += 1024) {
        float4 v = *reinterpret_cast<float4*>(&s_acc[n * 4]);
        *reinterpret_cast<float4*>(&agg[(b * 4096 + n) * 16 + co0]) = v;
    }
}

// ---------- dual-LDS-staged pool GEMM ----------
template <int F, int ELU>
__global__ __launch_bounds__(256) void k_pool2(const float* __restrict__ in,
                                               const float* __restrict__ P,
                                               float* __restrict__ out,
                                               int nout, int nin) {
    constexpr int FQ = F / 4;
    constexpr int TI = 256 / FQ;
    constexpr int KT = 64;
    constexpr int PS = KT + 4;
    __shared__ float s_p[TI * PS];
    __shared__ float4 s_in[KT * FQ];
    int tid = threadIdx.x;
    int fq = tid % FQ;
    int i = tid / FQ;
    int b = blockIdx.y;
    int gi = blockIdx.x * TI + i;
    int nchunk = nin / gridDim.z;
    int kbeg = blockIdx.z * nchunk;
    const float4* inb4 = reinterpret_cast<const float4*>(in + b * nin * F);
    float4 acc = make_float4(0.f, 0.f, 0.f, 0.f);

    for (int k0 = kbeg; k0 < kbeg + nchunk; k0 += KT) {
        __syncthreads();
        for (int idx = tid; idx < TI * (KT / 4); idx += 256) {
            int r = idx / (KT / 4), c = idx % (KT / 4);
            float4 v = *reinterpret_cast<const float4*>(&P[(blockIdx.x * TI + r) * nin + k0 + c * 4]);
            *reinterpret_cast<float4*>(&s_p[r * PS + c * 4]) = v;
        }
        for (int idx = tid; idx < KT * FQ; idx += 256) {
            float4 v = inb4[(size_t)(k0 + idx / FQ) * FQ + (idx % FQ)];
            if (ELU) {
                v.x = elu_f(v.x); v.y = elu_f(v.y);
                v.z = elu_f(v.z); v.w = elu_f(v.w);
            }
            s_in[idx] = v;
        }
        __syncthreads();
#pragma unroll 4
        for (int j = 0; j < KT; j += 4) {
            float4 pv = *reinterpret_cast<const float4*>(&s_p[i * PS + j]);
            float4 v0 = s_in[(j + 0) * FQ + fq];
            float4 v1 = s_in[(j + 1) * FQ + fq];
            float4 v2 = s_in[(j + 2) * FQ + fq];
            float4 v3 = s_in[(j + 3) * FQ + fq];
            acc.x = fmaf(pv.x, v0.x, acc.x); acc.y = fmaf(pv.x, v0.y, acc.y);
            acc.z = fmaf(pv.x, v0.z, acc.z); acc.w = fmaf(pv.x, v0.w, acc.w);
            acc.x = fmaf(pv.y, v1.x, acc.x); acc.y = fmaf(pv.y, v1.y, acc.y);
            acc.z = fmaf(pv.y, v1.z, acc.z); acc.w = fmaf(pv.y, v1.w, acc.w);
            acc.x = fmaf(pv.z, v2.x, acc.x); acc.y = fmaf(pv.z, v2.y, acc.y);
            acc.z = fmaf(pv.z, v2.z, acc.z); acc.w = fmaf(pv.z, v2.w, acc.w);
            acc.x = fmaf(pv.w, v3.x, acc.x); acc.y = fmaf(pv.w, v3.y, acc.y);
            acc.z = fmaf(pv.w, v3.z, acc.z); acc.w = fmaf(pv.w, v3.w, acc.w);
        }
    }
    float* o = out + ((size_t)b * nout + gi) * F + fq * 4;
    if (gridDim.z > 1) {
        atomicAdd(o + 0, acc.x); atomicAdd(o + 1, acc.y);
        atomicAdd(o + 2, acc.z); atomicAdd(o + 3, acc.w);
    } else {
        *reinterpret_cast<float4*>(o) = acc;
    }
}

__global__ __launch_bounds__(TPB) void k_pool_e(const float* __restrict__ in,
                                                const float* __restrict__ P,
                                                float* __restrict__ out,
                                                int nout, int nin, int F, int elu) {
    int t = blockIdx.x * blockDim.x + threadIdx.x;
    if (t >= 16 * nout * F) return;
    int f = t % F;
    int rest = t / F;
    int i = rest % nout;
    int b = rest / nout;
    const float* ip = in + b * nin * F + f;
    const float* pp = P + i * nin;
    float acc = 0.f;
    if (elu) {
#pragma unroll 4
        for (int j = 0; j < nin; ++j) acc = fmaf(pp[j], elu_f(ip[j * F]), acc);
    } else {
#pragma unroll 4
        for (int j = 0; j < nin; ++j) acc = fmaf(pp[j], ip[j * F], acc);
    }
    out[t] = acc;
}

// ---------- fused bottleneck ----------
__global__ __launch_bounds__(1024) void k_fc_fused2(
        const float* __restrict__ c5agg, const float* __restrict__ Pn1,
        const float* __restrict__ fce1_w, const float* __restrict__ fce1_b,
        const float* __restrict__ fce21_w, const float* __restrict__ fce21_b,
        const float* __restrict__ fce22_w, const float* __restrict__ fce22_b,
        const float* __restrict__ eps,
        const float* __restrict__ fcd3_w, const float* __restrict__ fcd3_b,
        const float* __restrict__ fcd4_w, const float* __restrict__ fcd4_b,
        const float* __restrict__ P1n,
        float* __restrict__ out_mu, float* __restrict__ out_lv,
        float* __restrict__ dec_in) {
    __shared__ float s0[256], s1[256], sz[32], sp[1024];
    int b = blockIdx.x, t = threadIdx.x;
    if (t < 256) {
        const float* ap = c5agg + b * 4096 + t;
        float acc = 0.f;
#pragma unroll
        for (int n = 0; n < 16; ++n) acc = fmaf(Pn1[n], elu_f(ap[n * 256]), acc);
        s0[t] = acc;
    }
    __syncthreads();
    {
        int q = t >> 8, co = t & 255;
        const float* w = fce1_w + co;
        float a = 0.f;
        int c0 = q * 64;
        for (int ci = 0; ci < 64; ci += 8) {
#pragma unroll
            for (int k = 0; k < 8; ++k) a = fmaf(s0[c0 + ci + k], w[(c0 + ci + k) * 256], a);
        }
        sp[t] = a;
    }
    __syncthreads();
    if (t < 256) s1[t] = elu_f(sp[t] + sp[t + 256] + sp[t + 512] + sp[t + 768] + fce1_b[t]);
    __syncthreads();
    if (t < 512) {
        int which = t >> 8, r = t & 255;
        int co = r & 31, q = r >> 5;
        const float* w = (which ? fce22_w : fce21_w) + co;
        float a = 0.f;
        int c0 = q * 32;
#pragma unroll
        for (int k = 0; k < 32; ++k) a = fmaf(s1[c0 + k], w[(c0 + k) * 32], a);
        sp[t] = a;
    }
    __syncthreads();
    if (t < 64) {
        int which = t >> 5, co = t & 31;
        float m = (which ? fce22_b : fce21_b)[co];
        int base = which * 256 + co;
#pragma unroll
        for (int q = 0; q < 8; ++q) m += sp[base + q * 32];
        if (which == 0) { out_mu[b * 32 + co] = m; s0[co] = m; }
        else            { out_lv[b * 32 + co] = m; s0[64 + co] = m; }
    }
    __syncthreads();
    if (t < 32) sz[t] = fmaf(eps[b * 32 + t], expf(0.5f * s0[64 + t]), s0[t]);
    __syncthreads();
    if (t < 256) {
        float d = fcd3_b[t];
#pragma unroll
        for (int ci = 0; ci < 32; ++ci) d = fmaf(sz[ci], fcd3_w[ci * 256 + t], d);
        s0[t] = elu_f(d);
    }
    __syncthreads();
    {
        int q = t >> 8, co = t & 255;
        const float* w = fcd4_w + co;
        float a = 0.f;
        int c0 = q * 64;
        for (int ci = 0; ci < 64; ci += 8) {
#pragma unroll
            for (int k = 0; k < 8; ++k) a = fmaf(s0[c0 + ci + k], w[(c0 + ci + k) * 256], a);
        }
        sp[t] = a;
    }
    __syncthreads();
    if (t < 256) s1[t] = elu_f(sp[t] + sp[t + 256] + sp[t + 512] + sp[t + 768] + fcd4_b[t]);
    __syncthreads();
    {
        float* op = dec_in + b * 4096;
        for (int idx = t; idx < 4096; idx += 1024) {
            int n = idx >> 8, f = idx & 255;
            op[idx] = P1n[n] * s1[f];
        }
    }
}

__global__ __launch_bounds__(TPB) void k_elu_out(const float* __restrict__ in,
                                                 float* __restrict__ out, int n) {
    int t = blockIdx.x * blockDim.x + threadIdx.x;
    if (t < n) out[t] = elu_f(in[t]);
}

extern "C" void kernel_launch(void* const* d_in, const int* in_sizes, int n_in,
                              void* d_out, int out_size, void* d_ws, size_t ws_size,
                              hipStream_t stream) {
    const float* x    = (const float*)d_in[0];
    const float* ea0  = (const float*)d_in[1];
    const float* ea1  = (const float*)d_in[2];
    const float* ea2  = (const float*)d_in[3];
    const float* ea3  = (const float*)d_in[4];
    const float* ea4  = (const float*)d_in[5];
    const float* P01  = (const float*)d_in[6];
    const float* P12  = (const float*)d_in[7];
    const float* P23  = (const float*)d_in[8];
    const float* P34  = (const float*)d_in[9];
    const float* Pn1  = (const float*)d_in[10];
    const float* P1n  = (const float*)d_in[11];
    const float* P43  = (const float*)d_in[12];
    const float* P32  = (const float*)d_in[13];
    const float* P21  = (const float*)d_in[14];
    const float* P10  = (const float*)d_in[15];
    const float* W_c1 = (const float*)d_in[16]; const float* r_c1 = (const float*)d_in[17]; const float* b_c1 = (const float*)d_in[18];
    const float* W_c2 = (const float*)d_in[19]; const float* r_c2 = (const float*)d_in[20]; const float* b_c2 = (const float*)d_in[21];
    const float* W_c3 = (const float*)d_in[22]; const float* r_c3 = (const float*)d_in[23]; const float* b_c3 = (const float*)d_in[24];
    const float* W_c4 = (const float*)d_in[25]; const float* r_c4 = (const float*)d_in[26]; const float* b_c4 = (const float*)d_in[27];
    const float* W_c5 = (const float*)d_in[28]; const float* r_c5 = (const float*)d_in[29]; const float* b_c5 = (const float*)d_in[30];
    const float* W_d5 = (const float*)d_in[31]; const float* r_d5 = (const float*)d_in[32]; const float* b_d5 = (const float*)d_in[33];
    const float* W_d4 = (const float*)d_in[34]; const float* r_d4 = (const float*)d_in[35]; const float* b_d4 = (const float*)d_in[36];
    const float* W_d3 = (const float*)d_in[37]; const float* r_d3 = (const float*)d_in[38]; const float* b_d3 = (const float*)d_in[39];
    const float* W_d2 = (const float*)d_in[40]; const float* r_d2 = (const float*)d_in[41]; const float* b_d2 = (const float*)d_in[42];
    const float* W_d1 = (const float*)d_in[43]; const float* r_d1 = (const float*)d_in[44]; const float* b_d1 = (const float*)d_in[45];
    const float* fce1_w  = (const float*)d_in[46]; const float* fce1_b  = (const float*)d_in[47];
    const float* fce21_w = (const float*)d_in[48]; const float* fce21_b = (const float*)d_in[49];
    const float* fce22_w = (const float*)d_in[50]; const float* fce22_b = (const float*)d_in[51];
    const float* fcd3_w  = (const float*)d_in[52]; const float* fcd3_b  = (const float*)d_in[53];
    const float* fcd4_w  = (const float*)d_in[54]; const float* fcd4_b  = (const float*)d_in[55];
    const float* eps  = (const float*)d_in[56];
    const void* ei0 = d_in[57];
    const void* ei1 = d_in[58];
    const void* ei2 = d_in[59];
    const void* ei3 = d_in[60];
    const void* ei4 = d_in[61];

    const int E0 = 393216, E1 = 98304, E2 = 24576, E3 = 6144, E4 = 1536;
    const int N0 = 65536, N1 = 16384, N2 = 4096, N3 = 1024, N4 = 256;

    float* sm   = (float*)d_ws;
    float* bufA = sm + 13824;
    float* bufB = bufA + 1048576;
    int*  flag  = (int*)(bufB + 262144);
    int*  ibase = flag + 64;
    // new layout: cur 87296 | rows 87301 | eids 523776
    int* cur  = ibase;
    int* rows = cur + 87296;
    int* eids = rows + 87301;
    const size_t WS_ALL = (size_t)(13824 + 1048576 + 262144 + 64 + 87296 + 87301 + 523776) * 4;
    // old layout (fallback): row0 65537 | cur0 65536 | eid0 393216
    int* o_row = ibase;
    int* o_cur = o_row + 65537;
    int* o_eid = o_cur + 65536;
    const size_t WS_OLD = (size_t)(13824 + 1048576 + 262144 + 64 + 524352) * 4;
    const bool bigA = ws_size >= WS_ALL;
    const bool big0 = ws_size >= WS_OLD;

    // row/eid offsets per level
    const int ROFF[5] = {0, 65537, 81922, 86019, 87044};
    const int EOFF[5] = {0, 393216, 491520, 516096, 522240};

    float* out = (float*)d_out;
    float* out_mu = out + 65536;
    float* out_lv = out + 66048;

    auto g = [](int n) { return dim3((unsigned)CDIV(n, TPB)); };

    k_detect<<<1, 64, 0, stream>>>((const int*)ei0, flag);

    if (bigA) {
        k_zero_i<<<g(87296), TPB, 0, stream>>>(cur, 87296);
        k_csr_count5<<<g(523776), TPB, 0, stream>>>(ei0, ei1, ei2, ei3, ei4, cur, flag);
        k_csr_scan5<<<5, 1024, 0, stream>>>(cur, rows);
        k_zero_i<<<g(87296), TPB, 0, stream>>>(cur, 87296);
        k_csr_fill5<<<g(523776), TPB, 0, stream>>>(ei0, ei1, ei2, ei3, ei4, rows, cur, eids, flag);

        // ---------------- encoder ----------------
        k_gather_c1<<<1024, 256, 0, stream>>>(x, ea0, ei0, W_c1, r_c1, b_c1,
                                              rows + ROFF[0], eids + EOFF[0], bufA, flag);
        k_zero<<<g(262144), TPB, 0, stream>>>(bufB, 262144);
        k_pool2<16, 1><<<dim3(16, 16, 4), 256, 0, stream>>>(bufA, P01, bufB, 1024, 4096);

        k_gW<16, 32, 1, 1><<<dim3(64, 8, 1), 256, 0, stream>>>(bufB, ea1, ei1, W_c2, r_c2, b_c2,
                                                               rows + ROFF[1], eids + EOFF[1], bufA, flag);
        k_zero<<<g(131072), TPB, 0, stream>>>(bufB, 131072);
        k_pool2<32, 1><<<dim3(8, 16, 2), 256, 0, stream>>>(bufA, P12, bufB, 256, 1024);

        k_gW<32, 64, 1, 1><<<dim3(16, 16, 1), 256, 0, stream>>>(bufB, ea2, ei2, W_c3, r_c3, b_c3,
                                                                rows + ROFF[2], eids + EOFF[2], bufA, flag);
        k_zero<<<g(65536), TPB, 0, stream>>>(bufB, 65536);
        k_pool2<64, 1><<<dim3(4, 16, 2), 256, 0, stream>>>(bufA, P23, bufB, 64, 256);

        k_root4<<<g(N3 * 128), TPB, 0, stream>>>(bufB, r_c4, b_c4, bufA, N3, 64, 128);
        k_gW<64, 128, 2, 0><<<dim3(4, 32, 2), 256, 0, stream>>>(bufB, ea3, ei3, W_c4, r_c4, b_c4,
                                                                rows + ROFF[3], eids + EOFF[3], bufA, flag);
        k_pool_e<<<g(16 * 16 * 128), TPB, 0, stream>>>(bufA, P34, bufB, 16, 64, 128, 1);

        k_root4<<<g(N4 * 256), TPB, 0, stream>>>(bufB, r_c5, b_c5, bufA, N4, 128, 256);
        k_gW<128, 256, 4, 0><<<dim3(1, 64, 4), 256, 0, stream>>>(bufB, ea4, ei4, W_c5, r_c5, b_c5,
                                                                 rows + ROFF[4], eids + EOFF[4], bufA, flag);

        k_fc_fused2<<<16, 1024, 0, stream>>>(bufA, Pn1,
                                             fce1_w, fce1_b, fce21_w, fce21_b, fce22_w, fce22_b,
                                             eps, fcd3_w, fcd3_b, fcd4_w, fcd4_b, P1n,
                                             out_mu, out_lv, bufA);

        // ---------------- decoder ----------------
        k_root4<<<g(N4 * 128), TPB, 0, stream>>>(bufA, r_d5, b_d5, bufB, N4, 256, 128);
        k_gW<256, 128, 8, 0><<<dim3(1, 32, 8), 256, 0, stream>>>(bufA, ea4, ei4, W_d5, r_d5, b_d5,
                                                                 rows + ROFF[4], eids + EOFF[4], bufB, flag);
        k_pool_e<<<g(16 * 64 * 128), TPB, 0, stream>>>(bufB, P43, bufA, 64, 16, 128, 1);

        k_root4<<<g(N3 * 64), TPB, 0, stream>>>(bufA, r_d4, b_d4, bufB, N3, 128, 64);
        k_gW<128, 64, 4, 0><<<dim3(4, 16, 4), 256, 0, stream>>>(bufA, ea3, ei3, W_d4, r_d4, b_d4,
                                                                rows + ROFF[3], eids + EOFF[3], bufB, flag);
        k_pool2<64, 1><<<dim3(16, 16, 1), 256, 0, stream>>>(bufB, P32, bufA, 256, 64);

        k_root4<<<g(N2 * 32), TPB, 0, stream>>>(bufA, r_d3, b_d3, bufB, N2, 64, 32);
        k_gW<64, 32, 2, 0><<<dim3(16, 8, 2), 256, 0, stream>>>(bufA, ea2, ei2, W_d3, r_d3, b_d3,
                                                               rows + ROFF[2], eids + EOFF[2], bufB, flag);
        k_pool2<32, 1><<<dim3(32, 16, 1), 256, 0, stream>>>(bufB, P21, bufA, 1024, 256);

        k_gW<32, 16, 1, 1><<<dim3(64, 4, 1), 256, 0, stream>>>(bufA, ea1, ei1, W_d2, r_d2, b_d2,
                                                               rows + ROFF[1], eids + EOFF[1], bufB, flag);
        k_pool2<16, 1><<<dim3(64, 16, 1), 256, 0, stream>>>(bufB, P10, bufA, 4096, 1024);

        k_gather_d1<<<1024, 256, 0, stream>>>(bufA, ea0, ei0, W_d1, r_d1, b_d1,
                                              rows + ROFF[0], eids + EOFF[0], out, flag);
        return;
    }

    // ================= fallback paths (r12 structure) =================
    if (big0) {
        k_zero_i<<<g(65536), TPB, 0, stream>>>(o_cur, 65536);
        k_csr_count<<<g(E0), TPB, 0, stream>>>(ei0, o_cur, E0, flag);
        k_csr_scan<<<1, 1024, 0, stream>>>(o_cur, o_row);
        k_zero_i<<<g(65536), TPB, 0, stream>>>(o_cur, 65536);
        k_csr_fill<<<g(E0), TPB, 0, stream>>>(ei0, o_row, o_cur, o_eid, E0, flag);
        k_gather_c1<<<1024, 256, 0, stream>>>(x, ea0, ei0, W_c1, r_c1, b_c1,
                                              o_row, o_eid, bufA, flag);
    } else {
        k_msg_c1<<<dim3(16, 4), 1024, 0, stream>>>(x, ea0, ei0, W_c1, r_c1, b_c1, bufA, flag);
    }
    k_zero<<<g(262144), TPB, 0, stream>>>(bufB, 262144);
    k_pool2<16, 1><<<dim3(16, 16, 4), 256, 0, stream>>>(bufA, P01, bufB, 1024, 4096);

    k_root4<<<g(N1 * 32), TPB, 0, stream>>>(bufB, r_c2, b_c2, bufA, N1, 16, 32);
    k_msg4<16, 32, 1><<<g(E1 * 8), TPB, 0, stream>>>(bufB, ea1, ei1, W_c2, bufA, E1, flag);
    k_zero<<<g(131072), TPB, 0, stream>>>(bufB, 131072);
    k_pool2<32, 1><<<dim3(8, 16, 2), 256, 0, stream>>>(bufA, P12, bufB, 256, 1024);

    k_root4<<<g(N2 * 64), TPB, 0, stream>>>(bufB, r_c3, b_c3, bufA, N2, 32, 64);
    k_msg4<32, 64, 1><<<g(E2 * 16), TPB, 0, stream>>>(bufB, ea2, ei2, W_c3, bufA, E2, flag);
    k_zero<<<g(65536), TPB, 0, stream>>>(bufB, 65536);
    k_pool2<64, 1><<<dim3(4, 16, 2), 256, 0, stream>>>(bufA, P23, bufB, 64, 256);

    k_root4<<<g(N3 * 128), TPB, 0, stream>>>(bufB, r_c4, b_c4, bufA, N3, 64, 128);
    k_msg4<64, 128, 1><<<g(E3 * 32), TPB, 0, stream>>>(bufB, ea3, ei3, W_c4, bufA, E3, flag);
    k_pool_e<<<g(16 * 16 * 128), TPB, 0, stream>>>(bufA, P34, bufB, 16, 64, 128, 1);

    k_root4<<<g(N4 * 256), TPB, 0, stream>>>(bufB, r_c5, b_c5, bufA, N4, 128, 256);
    k_msg4<128, 256, 2><<<g(E4 * 128), TPB, 0, stream>>>(bufB, ea4, ei4, W_c5, bufA, E4, flag);

    k_fc_fused2<<<16, 1024, 0, stream>>>(bufA, Pn1,
                                         fce1_w, fce1_b, fce21_w, fce21_b, fce22_w, fce22_b,
                                         eps, fcd3_w, fcd3_b, fcd4_w, fcd4_b, P1n,
                                         out_mu, out_lv, bufA);

    k_root4<<<g(N4 * 128), TPB, 0, stream>>>(bufA, r_d5, b_d5, bufB, N4, 256, 128);
    k_msg4<256, 128, 4><<<g(E4 * 128), TPB, 0, stream>>>(bufA, ea4, ei4, W_d5, bufB, E4, flag);
    k_pool_e<<<g(16 * 64 * 128), TPB, 0, stream>>>(bufB, P43, bufA, 64, 16, 128, 1);

    k_root4<<<g(N3 * 64), TPB, 0, stream>>>(bufA, r_d4, b_d4, bufB, N3, 128, 64);
    k_msg4<128, 64, 2><<<g(E3 * 32), TPB, 0, stream>>>(bufA, ea3, ei3, W_d4, bufB, E3, flag);
    k_pool2<64, 1><<<dim3(16, 16, 1), 256, 0, stream>>>(bufB, P32, bufA, 256, 64);

    k_root4<<<g(N2 * 32), TPB, 0, stream>>>(bufA, r_d3, b_d3, bufB, N2, 64, 32);
    k_msg4<64, 32, 1><<<g(E2 * 8), TPB, 0, stream>>>(bufA, ea2, ei2, W_d3, bufB, E2, flag);
    k_pool2<32, 1><<<dim3(32, 16, 1), 256, 0, stream>>>(bufB, P21, bufA, 1024, 256);

    k_root4<<<g(N1 * 16), TPB, 0, stream>>>(bufA, r_d2, b_d2, bufB, N1, 32, 16);
    k_msg4<32, 16, 1><<<g(E1 * 4), TPB, 0, stream>>>(bufA, ea1, ei1, W_d2, bufB, E1, flag);
    k_pool2<16, 1><<<dim3(64, 16, 1), 256, 0, stream>>>(bufB, P10, bufA, 4096, 1024);

    if (big0) {
        k_gather_d1<<<1024, 256, 0, stream>>>(bufA, ea0, ei0, W_d1, r_d1, b_d1,
                                              o_row, o_eid, out, flag);
    } else {
        k_root4<<<g(N0 * 1), TPB, 0, stream>>>(bufA, r_d1, b_d1, bufB, N0, 16, 1);
        k_msg_s<16, 1><<<g(E0), TPB, 0, stream>>>(bufA, ea0, ei0, W_d1, bufB, E0, flag);
        k_elu_out<<<g(N0), TPB, 0, stream>>>(bufB, out, 65536);
    }
}

// Round 14
// 1094.979 us; speedup vs baseline: 1.8519x; 1.8519x over previous
//
#include <hip/hip_runtime.h>
#include <hip/hip_bf16.h>

#define TPB 256
#define CDIV(a,b) (((a)+(b)-1)/(b))

__device__ __forceinline__ float elu_f(float v) {
    return v > 0.f ? v : expm1f(v);
}

__device__ __forceinline__ int ld_idx(const void* __restrict__ ei, int pos, int is64) {
    if (is64) return (int)((const long long*)ei)[pos];
    return ((const int*)ei)[pos];
}

__device__ __forceinline__ void spline_basis(const float* __restrict__ pseudo, int e,
                                             float bas[8], int kidx[8]) {
    float f[3]; int lo[3];
#pragma unroll
    for (int d = 0; d < 3; ++d) {
        float v = pseudo[e * 3 + d] * 4.f;
        float l = floorf(v);
        l = fminf(fmaxf(l, 0.f), 3.f);
        f[d] = v - l;
        lo[d] = (int)l;
    }
#pragma unroll
    for (int s = 0; s < 8; ++s) {
        int b0 = s & 1, b1 = (s >> 1) & 1, b2 = (s >> 2) & 1;
        bas[s] = (b0 ? f[0] : 1.f - f[0]) * (b1 ? f[1] : 1.f - f[1]) * (b2 ? f[2] : 1.f - f[2]);
        kidx[s] = (lo[0] + b0) + 5 * (lo[1] + b1) + 25 * (lo[2] + b2);
    }
}

__global__ void k_detect(const int* __restrict__ ei0_as_i32, int* __restrict__ flag) {
    if (threadIdx.x == 0 && blockIdx.x == 0) {
        int zeros = 0;
        for (int k = 0; k < 128; ++k)
            if (ei0_as_i32[2 * k + 1] == 0) zeros++;
        flag[0] = (zeros >= 120) ? 1 : 0;
    }
}

__global__ __launch_bounds__(TPB) void k_zero(float* __restrict__ p, int n) {
    int t = blockIdx.x * blockDim.x + threadIdx.x;
    if (t < n) p[t] = 0.f;
}

__global__ __launch_bounds__(TPB) void k_zero_i(int* __restrict__ p, int n) {
    int t = blockIdx.x * blockDim.x + threadIdx.x;
    if (t < n) p[t] = 0;
}

// =========== multi-level CSR (levels 0..4) ===========
__global__ __launch_bounds__(TPB) void k_csr_count5(const void* e0, const void* e1,
                                                    const void* e2, const void* e3,
                                                    const void* e4, int* __restrict__ cnt,
                                                    const int* __restrict__ flag) {
    int t = blockIdx.x * blockDim.x + threadIdx.x;
    if (t >= 523776) return;
    int is64 = flag[0];
    const void* ei; int e, E, noff;
    if (t < 393216)      { ei = e0; e = t;          E = 393216; noff = 0; }
    else if (t < 491520) { ei = e1; e = t - 393216; E = 98304;  noff = 65536; }
    else if (t < 516096) { ei = e2; e = t - 491520; E = 24576;  noff = 81920; }
    else if (t < 522240) { ei = e3; e = t - 516096; E = 6144;   noff = 86016; }
    else                 { ei = e4; e = t - 522240; E = 1536;   noff = 87040; }
    int dst = ld_idx(ei, E + e, is64);
    atomicAdd(&cnt[noff + dst], 1);
}

__global__ __launch_bounds__(1024) void k_csr_scan5(const int* __restrict__ cnt,
                                                    int* __restrict__ rows) {
    const int NODES[5] = {65536, 16384, 4096, 1024, 256};
    const int NOFF[5]  = {0, 65536, 81920, 86016, 87040};
    const int ROFF[5]  = {0, 65537, 81922, 86019, 87044};
    int l = blockIdx.x;
    int nodes = NODES[l];
    const int* c = cnt + NOFF[l];
    int* rp = rows + ROFF[l];
    __shared__ int s_part[1024];
    int t = threadIdx.x;
    int chunk = (nodes + 1023) >> 10;
    int b0 = t * chunk;
    int b1 = min(b0 + chunk, nodes);
    int sum = 0;
    for (int i = b0; i < b1; ++i) sum += c[i];
    s_part[t] = sum;
    __syncthreads();
    for (int off = 1; off < 1024; off <<= 1) {
        int v = (t >= off) ? s_part[t - off] : 0;
        __syncthreads();
        s_part[t] += v;
        __syncthreads();
    }
    int run = (t == 0) ? 0 : s_part[t - 1];
    for (int i = b0; i < b1; ++i) { rp[i] = run; run += c[i]; }
    if (t == 0) rp[nodes] = s_part[1023];
}

__global__ __launch_bounds__(TPB) void k_csr_fill5(const void* e0, const void* e1,
                                                   const void* e2, const void* e3,
                                                   const void* e4,
                                                   const int* __restrict__ rows,
                                                   int* __restrict__ cur,
                                                   int* __restrict__ eids,
                                                   const int* __restrict__ flag) {
    int t = blockIdx.x * blockDim.x + threadIdx.x;
    if (t >= 523776) return;
    int is64 = flag[0];
    const void* ei; int e, E, noff, roff, eoff;
    if (t < 393216)      { ei = e0; e = t;          E = 393216; noff = 0;     roff = 0;     eoff = 0; }
    else if (t < 491520) { ei = e1; e = t - 393216; E = 98304;  noff = 65536; roff = 65537; eoff = 393216; }
    else if (t < 516096) { ei = e2; e = t - 491520; E = 24576;  noff = 81920; roff = 81922; eoff = 491520; }
    else if (t < 522240) { ei = e3; e = t - 516096; E = 6144;   noff = 86016; roff = 86019; eoff = 516096; }
    else                 { ei = e4; e = t - 522240; E = 1536;   noff = 87040; roff = 87044; eoff = 522240; }
    int dst = ld_idx(ei, E + e, is64);
    int pos = rows[roff + dst] + atomicAdd(&cur[noff + dst], 1);
    eids[eoff + pos] = e;
}

// single-level CSR (fallback)
__global__ __launch_bounds__(TPB) void k_csr_count(const void* __restrict__ ei,
                                                   int* __restrict__ cnt, int E,
                                                   const int* __restrict__ flag) {
    int t = blockIdx.x * blockDim.x + threadIdx.x;
    if (t >= E) return;
    int dst = ld_idx(ei, E + t, flag[0]);
    atomicAdd(&cnt[dst], 1);
}

__global__ __launch_bounds__(1024) void k_csr_scan(const int* __restrict__ cnt,
                                                   int* __restrict__ row_ptr) {
    __shared__ int s_part[1024];
    int t = threadIdx.x;
    int base = t * 64;
    int sum = 0;
    for (int i = 0; i < 64; ++i) sum += cnt[base + i];
    s_part[t] = sum;
    __syncthreads();
    for (int off = 1; off < 1024; off <<= 1) {
        int v = (t >= off) ? s_part[t - off] : 0;
        __syncthreads();
        s_part[t] += v;
        __syncthreads();
    }
    int run = (t == 0) ? 0 : s_part[t - 1];
    for (int i = 0; i < 64; ++i) { row_ptr[base + i] = run; run += cnt[base + i]; }
    if (t == 1023) row_ptr[65536] = run;
}

__global__ __launch_bounds__(TPB) void k_csr_fill(const void* __restrict__ ei,
                                                  const int* __restrict__ row_ptr,
                                                  int* __restrict__ cur,
                                                  int* __restrict__ eid, int E,
                                                  const int* __restrict__ flag) {
    int t = blockIdx.x * blockDim.x + threadIdx.x;
    if (t >= E) return;
    int dst = ld_idx(ei, E + t, flag[0]);
    int pos = row_ptr[dst] + atomicAdd(&cur[dst], 1);
    eid[pos] = t;
}

// ---------- c1 gather ----------
__global__ __launch_bounds__(256) void k_gather_c1(const float* __restrict__ x,
                                                   const float* __restrict__ pseudo,
                                                   const void* __restrict__ ei,
                                                   const float* __restrict__ W,
                                                   const float* __restrict__ root,
                                                   const float* __restrict__ bias,
                                                   const int* __restrict__ row_ptr,
                                                   const int* __restrict__ eid,
                                                   float* __restrict__ agg,
                                                   const int* __restrict__ flag) {
    __shared__ float4 s_w[500];
    for (int i = threadIdx.x; i < 500; i += 256)
        s_w[i] = reinterpret_cast<const float4*>(W)[i];
    __syncthreads();
    int t = blockIdx.x * 256 + threadIdx.x;
    int n = t >> 2, cg = t & 3, co0 = cg * 4;
    int is64 = flag[0];
    float xn = x[n];
    float a0 = fmaf(xn, root[co0 + 0], bias[co0 + 0]);
    float a1 = fmaf(xn, root[co0 + 1], bias[co0 + 1]);
    float a2 = fmaf(xn, root[co0 + 2], bias[co0 + 2]);
    float a3 = fmaf(xn, root[co0 + 3], bias[co0 + 3]);
    int rb = row_ptr[n], re = row_ptr[n + 1];
    for (int idx = rb; idx < re; ++idx) {
        int e = eid[idx];
        int src = ld_idx(ei, e, is64);
        float bas[8]; int kidx[8];
        spline_basis(pseudo, e, bas, kidx);
        float xs = x[src];
        float m0 = 0.f, m1 = 0.f, m2 = 0.f, m3 = 0.f;
#pragma unroll
        for (int s = 0; s < 8; ++s) {
            float4 w = s_w[kidx[s] * 4 + cg];
            float bs = bas[s];
            m0 = fmaf(bs, w.x, m0);
            m1 = fmaf(bs, w.y, m1);
            m2 = fmaf(bs, w.z, m2);
            m3 = fmaf(bs, w.w, m3);
        }
        a0 = fmaf(xs, m0, a0);
        a1 = fmaf(xs, m1, a1);
        a2 = fmaf(xs, m2, a2);
        a3 = fmaf(xs, m3, a3);
    }
    float4 v = make_float4(a0, a1, a2, a3);
    *reinterpret_cast<float4*>(&agg[n * 16 + co0]) = v;
}

// ---------- d1 gather ----------
__global__ __launch_bounds__(256) void k_gather_d1(const float* __restrict__ xin,
                                                   const float* __restrict__ pseudo,
                                                   const void* __restrict__ ei,
                                                   const float* __restrict__ W,
                                                   const float* __restrict__ root,
                                                   const float* __restrict__ bias,
                                                   const int* __restrict__ row_ptr,
                                                   const int* __restrict__ eid,
                                                   float* __restrict__ outp,
                                                   const int* __restrict__ flag) {
    __shared__ float s_w[2000];
    for (int i = threadIdx.x; i < 2000; i += 256) s_w[i] = W[i];
    __syncthreads();
    int t = blockIdx.x * 256 + threadIdx.x;
    int n = t >> 2, l = t & 3;
    int is64 = flag[0];
    int rb = row_ptr[n], re = row_ptr[n + 1];
    float acc = 0.f;
    for (int idx = rb + l; idx < re; idx += 4) {
        int e = eid[idx];
        int src = ld_idx(ei, e, is64);
        float bas[8]; int kidx[8];
        spline_basis(pseudo, e, bas, kidx);
        const float4* xs4 = reinterpret_cast<const float4*>(xin + src * 16);
        float4 xv0 = xs4[0], xv1 = xs4[1], xv2 = xs4[2], xv3 = xs4[3];
        float m = 0.f;
#pragma unroll
        for (int s = 0; s < 8; ++s) {
            const float4* wp = reinterpret_cast<const float4*>(s_w + kidx[s] * 16);
            float4 w0 = wp[0], w1 = wp[1], w2 = wp[2], w3 = wp[3];
            float p = 0.f;
            p = fmaf(xv0.x, w0.x, p); p = fmaf(xv0.y, w0.y, p);
            p = fmaf(xv0.z, w0.z, p); p = fmaf(xv0.w, w0.w, p);
            p = fmaf(xv1.x, w1.x, p); p = fmaf(xv1.y, w1.y, p);
            p = fmaf(xv1.z, w1.z, p); p = fmaf(xv1.w, w1.w, p);
            p = fmaf(xv2.x, w2.x, p); p = fmaf(xv2.y, w2.y, p);
            p = fmaf(xv2.z, w2.z, p); p = fmaf(xv2.w, w2.w, p);
            p = fmaf(xv3.x, w3.x, p); p = fmaf(xv3.y, w3.y, p);
            p = fmaf(xv3.z, w3.z, p); p = fmaf(xv3.w, w3.w, p);
            m = fmaf(bas[s], p, m);
        }
        acc += m;
    }
    acc += __shfl_xor(acc, 1);
    acc += __shfl_xor(acc, 2);
    if (l == 0) {
        const float4* xr = reinterpret_cast<const float4*>(xin + n * 16);
        const float4* rr = reinterpret_cast<const float4*>(root);
        float r = bias[0];
#pragma unroll
        for (int q = 0; q < 4; ++q) {
            float4 xv = xr[q], rv = rr[q];
            r = fmaf(xv.x, rv.x, r); r = fmaf(xv.y, rv.y, r);
            r = fmaf(xv.z, rv.z, r); r = fmaf(xv.w, rv.w, r);
        }
        outp[n] = elu_f(r + acc);
    }
}

// ---------- mid-level CSR gather, W slice in LDS with PADDED row stride ----------
// Pad row to CPT+1 float4s: granule = (k*(CPT+1)+ci)&7 = (k+ci)&7 -> lanes with
// random kidx spread across all 8 bank-groups (fixes r13's 16-way conflict).
template <int CIN, int COUT, int CSPLIT, int IROOT>
__global__ __launch_bounds__(256) void k_gW(const float* __restrict__ x,
                                            const float* __restrict__ pseudo,
                                            const void* __restrict__ ei,
                                            const float* __restrict__ W,
                                            const float* __restrict__ root,
                                            const float* __restrict__ bias,
                                            const int* __restrict__ row_ptr,
                                            const int* __restrict__ eid,
                                            float* __restrict__ agg,
                                            const int* __restrict__ flag) {
    constexpr int COG = COUT / 4;
    constexpr int CPT = CIN / CSPLIT;   // = 16 at all call sites
    constexpr int PS = CPT + 1;
    __shared__ float4 s_w[125 * PS];
    int cg = blockIdx.y, cih = blockIdx.z;
    const float4* W4 = reinterpret_cast<const float4*>(W);
    for (int i = threadIdx.x; i < 125 * CPT; i += 256) {
        int k = i / CPT, ci = i - k * CPT;
        s_w[k * PS + ci] = W4[(k * CIN + cih * CPT + ci) * COG + cg];
    }
    __syncthreads();
    int n = blockIdx.x * 256 + threadIdx.x;
    int is64 = flag[0];
    int co0 = cg * 4;
    float4 acc = make_float4(0.f, 0.f, 0.f, 0.f);
    if (IROOT) {
        acc = reinterpret_cast<const float4*>(bias)[cg];
        const float* xp = x + (size_t)n * CIN;
        const float4* r4 = reinterpret_cast<const float4*>(root);
#pragma unroll
        for (int ci = 0; ci < CIN; ++ci) {
            float xv = xp[ci];
            float4 rv = r4[ci * COG + cg];
            acc.x = fmaf(xv, rv.x, acc.x); acc.y = fmaf(xv, rv.y, acc.y);
            acc.z = fmaf(xv, rv.z, acc.z); acc.w = fmaf(xv, rv.w, acc.w);
        }
    }
    int rb = row_ptr[n], re = row_ptr[n + 1];
    for (int idx = rb; idx < re; ++idx) {
        int e = eid[idx];
        int src = ld_idx(ei, e, is64);
        float bas[8]; int kidx[8];
        spline_basis(pseudo, e, bas, kidx);
        float xv[CPT];
        const float* xp = x + (size_t)src * CIN + cih * CPT;
#pragma unroll
        for (int ci = 0; ci < CPT; ++ci) xv[ci] = xp[ci];
#pragma unroll
        for (int s = 0; s < 8; ++s) {
            const float4* wp = s_w + kidx[s] * PS;
            float bs = bas[s];
#pragma unroll
            for (int ci = 0; ci < CPT; ++ci) {
                float bx = bs * xv[ci];
                float4 w = wp[ci];
                acc.x = fmaf(bx, w.x, acc.x); acc.y = fmaf(bx, w.y, acc.y);
                acc.z = fmaf(bx, w.z, acc.z); acc.w = fmaf(bx, w.w, acc.w);
            }
        }
    }
    float* o = agg + (size_t)n * COUT + co0;
    if (IROOT) {
        *reinterpret_cast<float4*>(o) = acc;
    } else {
        atomicAdd(o + 0, acc.x); atomicAdd(o + 1, acc.y);
        atomicAdd(o + 2, acc.z); atomicAdd(o + 3, acc.w);
    }
}

// root transform, cin%4==0
__global__ __launch_bounds__(TPB) void k_root4(const float* __restrict__ x,
                                               const float* __restrict__ root,
                                               const float* __restrict__ bias,
                                               float* __restrict__ out,
                                               int nnode, int cin, int cout) {
    int t = blockIdx.x * blockDim.x + threadIdx.x;
    if (t >= nnode * cout) return;
    int n = t / cout, co = t - n * cout;
    const float4* xr = reinterpret_cast<const float4*>(x + n * cin);
    float a0 = 0.f, a1 = 0.f, a2 = 0.f, a3 = 0.f;
    int q4 = cin >> 2;
    for (int q = 0; q < q4; ++q) {
        float4 xv = xr[q];
        const float* rp = root + (q * 4) * cout + co;
        a0 = fmaf(xv.x, rp[0], a0);
        a1 = fmaf(xv.y, rp[cout], a1);
        a2 = fmaf(xv.z, rp[2 * cout], a2);
        a3 = fmaf(xv.w, rp[3 * cout], a3);
    }
    out[t] = bias[co] + ((a0 + a1) + (a2 + a3));
}

// ---------- fallback atomic msg ----------
template <int CIN, int COUT, int CSPLIT>
__global__ __launch_bounds__(TPB) void k_msg4(const float* __restrict__ x,
                                              const float* __restrict__ pseudo,
                                              const void* __restrict__ ei,
                                              const float* __restrict__ W,
                                              float* __restrict__ agg, int E,
                                              const int* __restrict__ flag) {
    constexpr int COG = COUT / 4;
    constexpr int CPT = CIN / CSPLIT;
    int t = blockIdx.x * blockDim.x + threadIdx.x;
    if (t >= E * COG * CSPLIT) return;
    int is64 = flag[0];
    int cog = t % COG;
    int rest = t / COG;
    int cs = rest % CSPLIT;
    int e = rest / CSPLIT;
    int co0 = cog * 4;
    int src = ld_idx(ei, e, is64);
    int dst = ld_idx(ei, E + e, is64);
    float bas[8]; int kidx[8];
    spline_basis(pseudo, e, bas, kidx);
    int wof[8];
#pragma unroll
    for (int s = 0; s < 8; ++s) wof[s] = kidx[s] * CIN * COUT + co0;
    float a0 = 0.f, a1 = 0.f, a2 = 0.f, a3 = 0.f;
    const float* xp = x + src * CIN + cs * CPT;
    const int cbase = cs * CPT * COUT;
    for (int ci = 0; ci < CPT; ++ci) {
        float xv = xp[ci];
        int off = cbase + ci * COUT;
#pragma unroll
        for (int s = 0; s < 8; ++s) {
            float4 w = *reinterpret_cast<const float4*>(&W[wof[s] + off]);
            float bx = bas[s] * xv;
            a0 = fmaf(bx, w.x, a0);
            a1 = fmaf(bx, w.y, a1);
            a2 = fmaf(bx, w.z, a2);
            a3 = fmaf(bx, w.w, a3);
        }
    }
    float* ap = &agg[dst * COUT + co0];
    atomicAdd(ap + 0, a0);
    atomicAdd(ap + 1, a1);
    atomicAdd(ap + 2, a2);
    atomicAdd(ap + 3, a3);
}

template <int CIN, int COUT>
__global__ __launch_bounds__(TPB) void k_msg_s(const float* __restrict__ x,
                                               const float* __restrict__ pseudo,
                                               const void* __restrict__ ei,
                                               const float* __restrict__ W,
                                               float* __restrict__ agg, int E,
                                               const int* __restrict__ flag) {
    int t = blockIdx.x * blockDim.x + threadIdx.x;
    if (t >= E * COUT) return;
    int is64 = flag[0];
    int e = t / COUT, co = t - e * COUT;
    int src = ld_idx(ei, e, is64);
    int dst = ld_idx(ei, E + e, is64);
    float bas[8]; int kidx[8];
    spline_basis(pseudo, e, bas, kidx);
    float acc = 0.f;
    const float* xp = x + src * CIN;
    for (int ci = 0; ci < CIN; ++ci) {
        float xv = xp[ci];
#pragma unroll
        for (int s = 0; s < 8; ++s)
            acc = fmaf(bas[s] * xv, W[kidx[s] * CIN * COUT + ci * COUT + co], acc);
    }
    atomicAdd(&agg[dst * COUT + co], acc);
}

// c1 fallback (LDS accumulate)
__global__ __launch_bounds__(1024) void k_msg_c1(const float* __restrict__ x,
                                                 const float* __restrict__ pseudo,
                                                 const void* __restrict__ ei,
                                                 const float* __restrict__ W,
                                                 const float* __restrict__ root,
                                                 const float* __restrict__ bias,
                                                 float* __restrict__ agg,
                                                 const int* __restrict__ flag) {
    __shared__ float s_acc[4096 * 4];
    __shared__ float s_w[125 * 4];
    int b = blockIdx.x, cg = blockIdx.y, t = threadIdx.x;
    int co0 = cg * 4;
    int is64 = flag[0];
    if (t < 500) s_w[t] = W[(t >> 2) * 16 + co0 + (t & 3)];
    float r0 = root[co0], r1 = root[co0 + 1], r2 = root[co0 + 2], r3 = root[co0 + 3];
    float b0 = bias[co0], b1 = bias[co0 + 1], b2 = bias[co0 + 2], b3 = bias[co0 + 3];
    for (int n = t; n < 4096; n += 1024) {
        float xv = x[b * 4096 + n];
        s_acc[n * 4 + 0] = fmaf(xv, r0, b0);
        s_acc[n * 4 + 1] = fmaf(xv, r1, b1);
        s_acc[n * 4 + 2] = fmaf(xv, r2, b2);
        s_acc[n * 4 + 3] = fmaf(xv, r3, b3);
    }
    __syncthreads();
    int ebeg = b * 24576;
    for (int k = t; k < 24576; k += 1024) {
        int e = ebeg + k;
        int src = ld_idx(ei, e, is64);
        int dst = ld_idx(ei, 393216 + e, is64);
        float xv = x[src];
        float bas[8]; int kidx[8];
        spline_basis(pseudo, e, bas, kidx);
        float m0 = 0.f, m1 = 0.f, m2 = 0.f, m3 = 0.f;
#pragma unroll
        for (int s = 0; s < 8; ++s) {
            const float* wp = s_w + kidx[s] * 4;
            float bs = bas[s];
            m0 = fmaf(bs, wp[0], m0);
            m1 = fmaf(bs, wp[1], m1);
            m2 = fmaf(bs, wp[2], m2);
            m3 = fmaf(bs, wp[3], m3);
        }
        int dl = (dst - b * 4096) * 4;
        atomicAdd(&s_acc[dl + 0], m0 * xv);
        atomicAdd(&s_acc[dl + 1], m1 * xv);
        atomicAdd(&s_acc[dl + 2], m2 * xv);
        atomicAdd(&s_acc[dl + 3], m3 * xv);
    }
    __syncthreads();
    for (int n = t; n < 4096; n += 1024) {
        float4 v = *reinterpret_cast<float4*>(&s_acc[n * 4]);
        *reinterpret_cast<float4*>(&agg[(b * 4096 + n) * 16 + co0]) = v;
    }
}

// ---------- dual-LDS-staged pool GEMM ----------
template <int F, int ELU>
__global__ __launch_bounds__(256) void k_pool2(const float* __restrict__ in,
                                               const float* __restrict__ P,
                                               float* __restrict__ out,
                                               int nout, int nin) {
    constexpr int FQ = F / 4;
    constexpr int TI = 256 / FQ;
    constexpr int KT = 64;
    constexpr int PS = KT + 4;
    __shared__ float s_p[TI * PS];
    __shared__ float4 s_in[KT * FQ];
    int tid = threadIdx.x;
    int fq = tid % FQ;
    int i = tid / FQ;
    int b = blockIdx.y;
    int gi = blockIdx.x * TI + i;
    int nchunk = nin / gridDim.z;
    int kbeg = blockIdx.z * nchunk;
    const float4* inb4 = reinterpret_cast<const float4*>(in + b * nin * F);
    float4 acc = make_float4(0.f, 0.f, 0.f, 0.f);

    for (int k0 = kbeg; k0 < kbeg + nchunk; k0 += KT) {
        __syncthreads();
        for (int idx = tid; idx < TI * (KT / 4); idx += 256) {
            int r = idx / (KT / 4), c = idx % (KT / 4);
            float4 v = *reinterpret_cast<const float4*>(&P[(blockIdx.x * TI + r) * nin + k0 + c * 4]);
            *reinterpret_cast<float4*>(&s_p[r * PS + c * 4]) = v;
        }
        for (int idx = tid; idx < KT * FQ; idx += 256) {
            float4 v = inb4[(size_t)(k0 + idx / FQ) * FQ + (idx % FQ)];
            if (ELU) {
                v.x = elu_f(v.x); v.y = elu_f(v.y);
                v.z = elu_f(v.z); v.w = elu_f(v.w);
            }
            s_in[idx] = v;
        }
        __syncthreads();
#pragma unroll 4
        for (int j = 0; j < KT; j += 4) {
            float4 pv = *reinterpret_cast<const float4*>(&s_p[i * PS + j]);
            float4 v0 = s_in[(j + 0) * FQ + fq];
            float4 v1 = s_in[(j + 1) * FQ + fq];
            float4 v2 = s_in[(j + 2) * FQ + fq];
            float4 v3 = s_in[(j + 3) * FQ + fq];
            acc.x = fmaf(pv.x, v0.x, acc.x); acc.y = fmaf(pv.x, v0.y, acc.y);
            acc.z = fmaf(pv.x, v0.z, acc.z); acc.w = fmaf(pv.x, v0.w, acc.w);
            acc.x = fmaf(pv.y, v1.x, acc.x); acc.y = fmaf(pv.y, v1.y, acc.y);
            acc.z = fmaf(pv.y, v1.z, acc.z); acc.w = fmaf(pv.y, v1.w, acc.w);
            acc.x = fmaf(pv.z, v2.x, acc.x); acc.y = fmaf(pv.z, v2.y, acc.y);
            acc.z = fmaf(pv.z, v2.z, acc.z); acc.w = fmaf(pv.z, v2.w, acc.w);
            acc.x = fmaf(pv.w, v3.x, acc.x); acc.y = fmaf(pv.w, v3.y, acc.y);
            acc.z = fmaf(pv.w, v3.z, acc.z); acc.w = fmaf(pv.w, v3.w, acc.w);
        }
    }
    float* o = out + ((size_t)b * nout + gi) * F + fq * 4;
    if (gridDim.z > 1) {
        atomicAdd(o + 0, acc.x); atomicAdd(o + 1, acc.y);
        atomicAdd(o + 2, acc.z); atomicAdd(o + 3, acc.w);
    } else {
        *reinterpret_cast<float4*>(o) = acc;
    }
}

__global__ __launch_bounds__(TPB) void k_pool_e(const float* __restrict__ in,
                                                const float* __restrict__ P,
                                                float* __restrict__ out,
                                                int nout, int nin, int F, int elu) {
    int t = blockIdx.x * blockDim.x + threadIdx.x;
    if (t >= 16 * nout * F) return;
    int f = t % F;
    int rest = t / F;
    int i = rest % nout;
    int b = rest / nout;
    const float* ip = in + b * nin * F + f;
    const float* pp = P + i * nin;
    float acc = 0.f;
    if (elu) {
#pragma unroll 4
        for (int j = 0; j < nin; ++j) acc = fmaf(pp[j], elu_f(ip[j * F]), acc);
    } else {
#pragma unroll 4
        for (int j = 0; j < nin; ++j) acc = fmaf(pp[j], ip[j * F], acc);
    }
    out[t] = acc;
}

// ---------- fused bottleneck ----------
__global__ __launch_bounds__(1024) void k_fc_fused2(
        const float* __restrict__ c5agg, const float* __restrict__ Pn1,
        const float* __restrict__ fce1_w, const float* __restrict__ fce1_b,
        const float* __restrict__ fce21_w, const float* __restrict__ fce21_b,
        const float* __restrict__ fce22_w, const float* __restrict__ fce22_b,
        const float* __restrict__ eps,
        const float* __restrict__ fcd3_w, const float* __restrict__ fcd3_b,
        const float* __restrict__ fcd4_w, const float* __restrict__ fcd4_b,
        const float* __restrict__ P1n,
        float* __restrict__ out_mu, float* __restrict__ out_lv,
        float* __restrict__ dec_in) {
    __shared__ float s0[256], s1[256], sz[32], sp[1024];
    int b = blockIdx.x, t = threadIdx.x;
    if (t < 256) {
        const float* ap = c5agg + b * 4096 + t;
        float acc = 0.f;
#pragma unroll
        for (int n = 0; n < 16; ++n) acc = fmaf(Pn1[n], elu_f(ap[n * 256]), acc);
        s0[t] = acc;
    }
    __syncthreads();
    {
        int q = t >> 8, co = t & 255;
        const float* w = fce1_w + co;
        float a = 0.f;
        int c0 = q * 64;
        for (int ci = 0; ci < 64; ci += 8) {
#pragma unroll
            for (int k = 0; k < 8; ++k) a = fmaf(s0[c0 + ci + k], w[(c0 + ci + k) * 256], a);
        }
        sp[t] = a;
    }
    __syncthreads();
    if (t < 256) s1[t] = elu_f(sp[t] + sp[t + 256] + sp[t + 512] + sp[t + 768] + fce1_b[t]);
    __syncthreads();
    if (t < 512) {
        int which = t >> 8, r = t & 255;
        int co = r & 31, q = r >> 5;
        const float* w = (which ? fce22_w : fce21_w) + co;
        float a = 0.f;
        int c0 = q * 32;
#pragma unroll
        for (int k = 0; k < 32; ++k) a = fmaf(s1[c0 + k], w[(c0 + k) * 32], a);
        sp[t] = a;
    }
    __syncthreads();
    if (t < 64) {
        int which = t >> 5, co = t & 31;
        float m = (which ? fce22_b : fce21_b)[co];
        int base = which * 256 + co;
#pragma unroll
        for (int q = 0; q < 8; ++q) m += sp[base + q * 32];
        if (which == 0) { out_mu[b * 32 + co] = m; s0[co] = m; }
        else            { out_lv[b * 32 + co] = m; s0[64 + co] = m; }
    }
    __syncthreads();
    if (t < 32) sz[t] = fmaf(eps[b * 32 + t], expf(0.5f * s0[64 + t]), s0[t]);
    __syncthreads();
    if (t < 256) {
        float d = fcd3_b[t];
#pragma unroll
        for (int ci = 0; ci < 32; ++ci) d = fmaf(sz[ci], fcd3_w[ci * 256 + t], d);
        s0[t] = elu_f(d);
    }
    __syncthreads();
    {
        int q = t >> 8, co = t & 255;
        const float* w = fcd4_w + co;
        float a = 0.f;
        int c0 = q * 64;
        for (int ci = 0; ci < 64; ci += 8) {
#pragma unroll
            for (int k = 0; k < 8; ++k) a = fmaf(s0[c0 + ci + k], w[(c0 + ci + k) * 256], a);
        }
        sp[t] = a;
    }
    __syncthreads();
    if (t < 256) s1[t] = elu_f(sp[t] + sp[t + 256] + sp[t + 512] + sp[t + 768] + fcd4_b[t]);
    __syncthreads();
    {
        float* op = dec_in + b * 4096;
        for (int idx = t; idx < 4096; idx += 1024) {
            int n = idx >> 8, f = idx & 255;
            op[idx] = P1n[n] * s1[f];
        }
    }
}

__global__ __launch_bounds__(TPB) void k_elu_out(const float* __restrict__ in,
                                                 float* __restrict__ out, int n) {
    int t = blockIdx.x * blockDim.x + threadIdx.x;
    if (t < n) out[t] = elu_f(in[t]);
}

extern "C" void kernel_launch(void* const* d_in, const int* in_sizes, int n_in,
                              void* d_out, int out_size, void* d_ws, size_t ws_size,
                              hipStream_t stream) {
    const float* x    = (const float*)d_in[0];
    const float* ea0  = (const float*)d_in[1];
    const float* ea1  = (const float*)d_in[2];
    const float* ea2  = (const float*)d_in[3];
    const float* ea3  = (const float*)d_in[4];
    const float* ea4  = (const float*)d_in[5];
    const float* P01  = (const float*)d_in[6];
    const float* P12  = (const float*)d_in[7];
    const float* P23  = (const float*)d_in[8];
    const float* P34  = (const float*)d_in[9];
    const float* Pn1  = (const float*)d_in[10];
    const float* P1n  = (const float*)d_in[11];
    const float* P43  = (const float*)d_in[12];
    const float* P32  = (const float*)d_in[13];
    const float* P21  = (const float*)d_in[14];
    const float* P10  = (const float*)d_in[15];
    const float* W_c1 = (const float*)d_in[16]; const float* r_c1 = (const float*)d_in[17]; const float* b_c1 = (const float*)d_in[18];
    const float* W_c2 = (const float*)d_in[19]; const float* r_c2 = (const float*)d_in[20]; const float* b_c2 = (const float*)d_in[21];
    const float* W_c3 = (const float*)d_in[22]; const float* r_c3 = (const float*)d_in[23]; const float* b_c3 = (const float*)d_in[24];
    const float* W_c4 = (const float*)d_in[25]; const float* r_c4 = (const float*)d_in[26]; const float* b_c4 = (const float*)d_in[27];
    const float* W_c5 = (const float*)d_in[28]; const float* r_c5 = (const float*)d_in[29]; const float* b_c5 = (const float*)d_in[30];
    const float* W_d5 = (const float*)d_in[31]; const float* r_d5 = (const float*)d_in[32]; const float* b_d5 = (const float*)d_in[33];
    const float* W_d4 = (const float*)d_in[34]; const float* r_d4 = (const float*)d_in[35]; const float* b_d4 = (const float*)d_in[36];
    const float* W_d3 = (const float*)d_in[37]; const float* r_d3 = (const float*)d_in[38]; const float* b_d3 = (const float*)d_in[39];
    const float* W_d2 = (const float*)d_in[40]; const float* r_d2 = (const float*)d_in[41]; const float* b_d2 = (const float*)d_in[42];
    const float* W_d1 = (const float*)d_in[43]; const float* r_d1 = (const float*)d_in[44]; const float* b_d1 = (const float*)d_in[45];
    const float* fce1_w  = (const float*)d_in[46]; const float* fce1_b  = (const float*)d_in[47];
    const float* fce21_w = (const float*)d_in[48]; const float* fce21_b = (const float*)d_in[49];
    const float* fce22_w = (const float*)d_in[50]; const float* fce22_b = (const float*)d_in[51];
    const float* fcd3_w  = (const float*)d_in[52]; const float* fcd3_b  = (const float*)d_in[53];
    const float* fcd4_w  = (const float*)d_in[54]; const float* fcd4_b  = (const float*)d_in[55];
    const float* eps  = (const float*)d_in[56];
    const void* ei0 = d_in[57];
    const void* ei1 = d_in[58];
    const void* ei2 = d_in[59];
    const void* ei3 = d_in[60];
    const void* ei4 = d_in[61];

    const int E0 = 393216, E1 = 98304, E2 = 24576, E3 = 6144, E4 = 1536;
    const int N0 = 65536, N1 = 16384, N2 = 4096, N3 = 1024, N4 = 256;

    float* sm   = (float*)d_ws;
    float* bufA = sm + 13824;
    float* bufB = bufA + 1048576;
    int*  flag  = (int*)(bufB + 262144);
    int*  ibase = flag + 64;
    int* cur  = ibase;
    int* rows = cur + 87296;
    int* eids = rows + 87301;
    const size_t WS_ALL = (size_t)(13824 + 1048576 + 262144 + 64 + 87296 + 87301 + 523776) * 4;
    int* o_row = ibase;
    int* o_cur = o_row + 65537;
    int* o_eid = o_cur + 65536;
    const size_t WS_OLD = (size_t)(13824 + 1048576 + 262144 + 64 + 524352) * 4;
    const bool bigA = ws_size >= WS_ALL;
    const bool big0 = ws_size >= WS_OLD;

    const int ROFF[5] = {0, 65537, 81922, 86019, 87044};
    const int EOFF[5] = {0, 393216, 491520, 516096, 522240};

    float* out = (float*)d_out;
    float* out_mu = out + 65536;
    float* out_lv = out + 66048;

    auto g = [](int n) { return dim3((unsigned)CDIV(n, TPB)); };

    k_detect<<<1, 64, 0, stream>>>((const int*)ei0, flag);

    if (bigA) {
        k_zero_i<<<g(87296), TPB, 0, stream>>>(cur, 87296);
        k_csr_count5<<<g(523776), TPB, 0, stream>>>(ei0, ei1, ei2, ei3, ei4, cur, flag);
        k_csr_scan5<<<5, 1024, 0, stream>>>(cur, rows);
        k_zero_i<<<g(87296), TPB, 0, stream>>>(cur, 87296);
        k_csr_fill5<<<g(523776), TPB, 0, stream>>>(ei0, ei1, ei2, ei3, ei4, rows, cur, eids, flag);

        // ---------------- encoder ----------------
        k_gather_c1<<<1024, 256, 0, stream>>>(x, ea0, ei0, W_c1, r_c1, b_c1,
                                              rows + ROFF[0], eids + EOFF[0], bufA, flag);
        k_zero<<<g(262144), TPB, 0, stream>>>(bufB, 262144);
        k_pool2<16, 1><<<dim3(16, 16, 4), 256, 0, stream>>>(bufA, P01, bufB, 1024, 4096);

        k_gW<16, 32, 1, 1><<<dim3(64, 8, 1), 256, 0, stream>>>(bufB, ea1, ei1, W_c2, r_c2, b_c2,
                                                               rows + ROFF[1], eids + EOFF[1], bufA, flag);
        k_zero<<<g(131072), TPB, 0, stream>>>(bufB, 131072);
        k_pool2<32, 1><<<dim3(8, 16, 2), 256, 0, stream>>>(bufA, P12, bufB, 256, 1024);

        k_root4<<<g(N2 * 64), TPB, 0, stream>>>(bufB, r_c3, b_c3, bufA, N2, 32, 64);
        k_gW<32, 64, 2, 0><<<dim3(16, 16, 2), 256, 0, stream>>>(bufB, ea2, ei2, W_c3, r_c3, b_c3,
                                                                rows + ROFF[2], eids + EOFF[2], bufA, flag);
        k_zero<<<g(65536), TPB, 0, stream>>>(bufB, 65536);
        k_pool2<64, 1><<<dim3(4, 16, 2), 256, 0, stream>>>(bufA, P23, bufB, 64, 256);

        k_root4<<<g(N3 * 128), TPB, 0, stream>>>(bufB, r_c4, b_c4, bufA, N3, 64, 128);
        k_gW<64, 128, 4, 0><<<dim3(4, 32, 4), 256, 0, stream>>>(bufB, ea3, ei3, W_c4, r_c4, b_c4,
                                                                rows + ROFF[3], eids + EOFF[3], bufA, flag);
        k_pool_e<<<g(16 * 16 * 128), TPB, 0, stream>>>(bufA, P34, bufB, 16, 64, 128, 1);

        k_root4<<<g(N4 * 256), TPB, 0, stream>>>(bufB, r_c5, b_c5, bufA, N4, 128, 256);
        k_gW<128, 256, 8, 0><<<dim3(1, 64, 8), 256, 0, stream>>>(bufB, ea4, ei4, W_c5, r_c5, b_c5,
                                                                 rows + ROFF[4], eids + EOFF[4], bufA, flag);

        k_fc_fused2<<<16, 1024, 0, stream>>>(bufA, Pn1,
                                             fce1_w, fce1_b, fce21_w, fce21_b, fce22_w, fce22_b,
                                             eps, fcd3_w, fcd3_b, fcd4_w, fcd4_b, P1n,
                                             out_mu, out_lv, bufA);

        // ---------------- decoder ----------------
        k_root4<<<g(N4 * 128), TPB, 0, stream>>>(bufA, r_d5, b_d5, bufB, N4, 256, 128);
        k_gW<256, 128, 16, 0><<<dim3(1, 32, 16), 256, 0, stream>>>(bufA, ea4, ei4, W_d5, r_d5, b_d5,
                                                                   rows + ROFF[4], eids + EOFF[4], bufB, flag);
        k_pool_e<<<g(16 * 64 * 128), TPB, 0, stream>>>(bufB, P43, bufA, 64, 16, 128, 1);

        k_root4<<<g(N3 * 64), TPB, 0, stream>>>(bufA, r_d4, b_d4, bufB, N3, 128, 64);
        k_gW<128, 64, 8, 0><<<dim3(4, 16, 8), 256, 0, stream>>>(bufA, ea3, ei3, W_d4, r_d4, b_d4,
                                                                rows + ROFF[3], eids + EOFF[3], bufB, flag);
        k_pool2<64, 1><<<dim3(16, 16, 1), 256, 0, stream>>>(bufB, P32, bufA, 256, 64);

        k_root4<<<g(N2 * 32), TPB, 0, stream>>>(bufA, r_d3, b_d3, bufB, N2, 64, 32);
        k_gW<64, 32, 4, 0><<<dim3(16, 8, 4), 256, 0, stream>>>(bufA, ea2, ei2, W_d3, r_d3, b_d3,
                                                               rows + ROFF[2], eids + EOFF[2], bufB, flag);
        k_pool2<32, 1><<<dim3(32, 16, 1), 256, 0, stream>>>(bufB, P21, bufA, 1024, 256);

        k_root4<<<g(N1 * 16), TPB, 0, stream>>>(bufA, r_d2, b_d2, bufB, N1, 32, 16);
        k_gW<32, 16, 2, 0><<<dim3(64, 4, 2), 256, 0, stream>>>(bufA, ea1, ei1, W_d2, r_d2, b_d2,
                                                               rows + ROFF[1], eids + EOFF[1], bufB, flag);
        k_pool2<16, 1><<<dim3(64, 16, 1), 256, 0, stream>>>(bufB, P10, bufA, 4096, 1024);

        k_gather_d1<<<1024, 256, 0, stream>>>(bufA, ea0, ei0, W_d1, r_d1, b_d1,
                                              rows + ROFF[0], eids + EOFF[0], out, flag);
        return;
    }

    // ================= fallback paths =================
    if (big0) {
        k_zero_i<<<g(65536), TPB, 0, stream>>>(o_cur, 65536);
        k_csr_count<<<g(E0), TPB, 0, stream>>>(ei0, o_cur, E0, flag);
        k_csr_scan<<<1, 1024, 0, stream>>>(o_cur, o_row);
        k_zero_i<<<g(65536), TPB, 0, stream>>>(o_cur, 65536);
        k_csr_fill<<<g(E0), TPB, 0, stream>>>(ei0, o_row, o_cur, o_eid, E0, flag);
        k_gather_c1<<<1024, 256, 0, stream>>>(x, ea0, ei0, W_c1, r_c1, b_c1,
                                              o_row, o_eid, bufA, flag);
    } else {
        k_msg_c1<<<dim3(16, 4), 1024, 0, stream>>>(x, ea0, ei0, W_c1, r_c1, b_c1, bufA, flag);
    }
    k_zero<<<g(262144), TPB, 0, stream>>>(bufB, 262144);
    k_pool2<16, 1><<<dim3(16, 16, 4), 256, 0, stream>>>(bufA, P01, bufB, 1024, 4096);

    k_root4<<<g(N1 * 32), TPB, 0, stream>>>(bufB, r_c2, b_c2, bufA, N1, 16, 32);
    k_msg4<16, 32, 1><<<g(E1 * 8), TPB, 0, stream>>>(bufB, ea1, ei1, W_c2, bufA, E1, flag);
    k_zero<<<g(131072), TPB, 0, stream>>>(bufB, 131072);
    k_pool2<32, 1><<<dim3(8, 16, 2), 256, 0, stream>>>(bufA, P12, bufB, 256, 1024);

    k_root4<<<g(N2 * 64), TPB, 0, stream>>>(bufB, r_c3, b_c3, bufA, N2, 32, 64);
    k_msg4<32, 64, 1><<<g(E2 * 16), TPB, 0, stream>>>(bufB, ea2, ei2, W_c3, bufA, E2, flag);
    k_zero<<<g(65536), TPB, 0, stream>>>(bufB, 65536);
    k_pool2<64, 1><<<dim3(4, 16, 2), 256, 0, stream>>>(bufA, P23, bufB, 64, 256);

    k_root4<<<g(N3 * 128), TPB, 0, stream>>>(bufB, r_c4, b_c4, bufA, N3, 64, 128);
    k_msg4<64, 128, 1><<<g(E3 * 32), TPB, 0, stream>>>(bufB, ea3, ei3, W_c4, bufA, E3, flag);
    k_pool_e<<<g(16 * 16 * 128), TPB, 0, stream>>>(bufA, P34, bufB, 16, 64, 128, 1);

    k_root4<<<g(N4 * 256), TPB, 0, stream>>>(bufB, r_c5, b_c5, bufA, N4, 128, 256);
    k_msg4<128, 256, 2><<<g(E4 * 128), TPB, 0, stream>>>(bufB, ea4, ei4, W_c5, bufA, E4, flag);

    k_fc_fused2<<<16, 1024, 0, stream>>>(bufA, Pn1,
                                         fce1_w, fce1_b, fce21_w, fce21_b, fce22_w, fce22_b,
                                         eps, fcd3_w, fcd3_b, fcd4_w, fcd4_b, P1n,
                                         out_mu, out_lv, bufA);

    k_root4<<<g(N4 * 128), TPB, 0, stream>>>(bufA, r_d5, b_d5, bufB, N4, 256, 128);
    k_msg4<256, 128, 4><<<g(E4 * 128), TPB, 0, stream>>>(bufA, ea4, ei4, W_d5, bufB, E4, flag);
    k_pool_e<<<g(16 * 64 * 128), TPB, 0, stream>>>(bufB, P43, bufA, 64, 16, 128, 1);

    k_root4<<<g(N3 * 64), TPB, 0, stream>>>(bufA, r_d4, b_d4, bufB, N3, 128, 64);
    k_msg4<128, 64, 2><<<g(E3 * 32), TPB, 0, stream>>>(bufA, ea3, ei3, W_d4, bufB, E3, flag);
    k_pool2<64, 1><<<dim3(16, 16, 1), 256, 0, stream>>>(bufB, P32, bufA, 256, 64);

    k_root4<<<g(N2 * 32), TPB, 0, stream>>>(bufA, r_d3, b_d3, bufB, N2, 64, 32);
    k_msg4<64, 32, 1><<<g(E2 * 8), TPB, 0, stream>>>(bufA, ea2, ei2, W_d3, bufB, E2, flag);
    k_pool2<32, 1><<<dim3(32, 16, 1), 256, 0, stream>>>(bufB, P21, bufA, 1024, 256);

    k_root4<<<g(N1 * 16), TPB, 0, stream>>>(bufA, r_d2, b_d2, bufB, N1, 32, 16);
    k_msg4<32, 16, 1><<<g(E1 * 4), TPB, 0, stream>>>(bufA, ea1, ei1, W_d2, bufB, E1, flag);
    k_pool2<16, 1><<<dim3(64, 16, 1), 256, 0, stream>>>(bufB, P10, bufA, 4096, 1024);

    if (big0) {
        k_gather_d1<<<1024, 256, 0, stream>>>(bufA, ea0, ei0, W_d1, r_d1, b_d1,
                                              o_row, o_eid, out, flag);
    } else {
        k_root4<<<g(N0 * 1), TPB, 0, stream>>>(bufA, r_d1, b_d1, bufB, N0, 16, 1);
        k_msg_s<16, 1><<<g(E0), TPB, 0, stream>>>(bufA, ea0, ei0, W_d1, bufB, E0, flag);
        k_elu_out<<<g(N0), TPB, 0, stream>>>(bufB, out, 65536);
    }
}

// Round 15
// 964.454 us; speedup vs baseline: 2.1026x; 1.1353x over previous
//
#include <hip/hip_runtime.h>
#include <hip/hip_bf16.h>

#define TPB 256
#define CDIV(a,b) (((a)+(b)-1)/(b))

__device__ __forceinline__ float elu_f(float v) {
    return v > 0.f ? v : expm1f(v);
}

__device__ __forceinline__ int ld_idx(const void* __restrict__ ei, int pos, int is64) {
    if (is64) return (int)((const long long*)ei)[pos];
    return ((const int*)ei)[pos];
}

__device__ __forceinline__ void spline_basis(const float* __restrict__ pseudo, int e,
                                             float bas[8], int kidx[8]) {
    float f[3]; int lo[3];
#pragma unroll
    for (int d = 0; d < 3; ++d) {
        float v = pseudo[e * 3 + d] * 4.f;
        float l = floorf(v);
        l = fminf(fmaxf(l, 0.f), 3.f);
        f[d] = v - l;
        lo[d] = (int)l;
    }
#pragma unroll
    for (int s = 0; s < 8; ++s) {
        int b0 = s & 1, b1 = (s >> 1) & 1, b2 = (s >> 2) & 1;
        bas[s] = (b0 ? f[0] : 1.f - f[0]) * (b1 ? f[1] : 1.f - f[1]) * (b2 ? f[2] : 1.f - f[2]);
        kidx[s] = (lo[0] + b0) + 5 * (lo[1] + b1) + 25 * (lo[2] + b2);
    }
}

__global__ void k_detect(const int* __restrict__ ei0_as_i32, int* __restrict__ flag) {
    if (threadIdx.x == 0 && blockIdx.x == 0) {
        int zeros = 0;
        for (int k = 0; k < 128; ++k)
            if (ei0_as_i32[2 * k + 1] == 0) zeros++;
        flag[0] = (zeros >= 120) ? 1 : 0;
    }
}

__global__ __launch_bounds__(TPB) void k_zero(float* __restrict__ p, int n) {
    int t = blockIdx.x * blockDim.x + threadIdx.x;
    if (t < n) p[t] = 0.f;
}

__global__ __launch_bounds__(TPB) void k_zero_i(int* __restrict__ p, int n) {
    int t = blockIdx.x * blockDim.x + threadIdx.x;
    if (t < n) p[t] = 0;
}

// =========== multi-level CSR (levels 0..4) ===========
__global__ __launch_bounds__(TPB) void k_csr_count5(const void* e0, const void* e1,
                                                    const void* e2, const void* e3,
                                                    const void* e4, int* __restrict__ cnt,
                                                    const int* __restrict__ flag) {
    int t = blockIdx.x * blockDim.x + threadIdx.x;
    if (t >= 523776) return;
    int is64 = flag[0];
    const void* ei; int e, E, noff;
    if (t < 393216)      { ei = e0; e = t;          E = 393216; noff = 0; }
    else if (t < 491520) { ei = e1; e = t - 393216; E = 98304;  noff = 65536; }
    else if (t < 516096) { ei = e2; e = t - 491520; E = 24576;  noff = 81920; }
    else if (t < 522240) { ei = e3; e = t - 516096; E = 6144;   noff = 86016; }
    else                 { ei = e4; e = t - 522240; E = 1536;   noff = 87040; }
    int dst = ld_idx(ei, E + e, is64);
    atomicAdd(&cnt[noff + dst], 1);
}

// hierarchical scan: A (per-block exclusive) -> B (block sums) -> C (add offsets)
__device__ __forceinline__ void lvl_of_block(int b, int& l, int& lb) {
    if (b < 256)      { l = 0; lb = b; }
    else if (b < 320) { l = 1; lb = b - 256; }
    else if (b < 336) { l = 2; lb = b - 320; }
    else if (b < 340) { l = 3; lb = b - 336; }
    else              { l = 4; lb = b - 340; }
}

__global__ __launch_bounds__(256) void k_scan_a(const int* __restrict__ cnt,
                                                int* __restrict__ rows,
                                                int* __restrict__ bsum) {
    const int NOFF[5] = {0, 65536, 81920, 86016, 87040};
    const int ROFF[5] = {0, 65537, 81922, 86019, 87044};
    __shared__ int s[256];
    int l, lb; lvl_of_block(blockIdx.x, l, lb);
    int t = threadIdx.x;
    int i = lb * 256 + t;
    int v = cnt[NOFF[l] + i];
    s[t] = v;
    __syncthreads();
    for (int off = 1; off < 256; off <<= 1) {
        int u = (t >= off) ? s[t - off] : 0;
        __syncthreads();
        s[t] += u;
        __syncthreads();
    }
    rows[ROFF[l] + i] = s[t] - v;
    if (t == 255) bsum[blockIdx.x] = s[255];
}

__global__ __launch_bounds__(256) void k_scan_b(int* __restrict__ bsum,
                                                int* __restrict__ rows) {
    const int NB[5]    = {256, 64, 16, 4, 1};
    const int BOFF[5]  = {0, 256, 320, 336, 340};
    const int ROFF[5]  = {0, 65537, 81922, 86019, 87044};
    const int NODES[5] = {65536, 16384, 4096, 1024, 256};
    __shared__ int s[256];
    int l = blockIdx.x, t = threadIdx.x;
    int nb = NB[l];
    int v = (t < nb) ? bsum[BOFF[l] + t] : 0;
    s[t] = v;
    __syncthreads();
    for (int off = 1; off < 256; off <<= 1) {
        int u = (t >= off) ? s[t - off] : 0;
        __syncthreads();
        s[t] += u;
        __syncthreads();
    }
    if (t < nb) bsum[BOFF[l] + t] = s[t] - v;
    if (t == 0) rows[ROFF[l] + NODES[l]] = s[255];
}

__global__ __launch_bounds__(256) void k_scan_c(const int* __restrict__ bsum,
                                                int* __restrict__ rows) {
    const int ROFF[5] = {0, 65537, 81922, 86019, 87044};
    int l, lb; lvl_of_block(blockIdx.x, l, lb);
    rows[ROFF[l] + lb * 256 + threadIdx.x] += bsum[blockIdx.x];
}

__global__ __launch_bounds__(TPB) void k_csr_fill5(const void* e0, const void* e1,
                                                   const void* e2, const void* e3,
                                                   const void* e4,
                                                   const int* __restrict__ rows,
                                                   int* __restrict__ cur,
                                                   int* __restrict__ eids,
                                                   const int* __restrict__ flag) {
    int t = blockIdx.x * blockDim.x + threadIdx.x;
    if (t >= 523776) return;
    int is64 = flag[0];
    const void* ei; int e, E, noff, roff, eoff;
    if (t < 393216)      { ei = e0; e = t;          E = 393216; noff = 0;     roff = 0;     eoff = 0; }
    else if (t < 491520) { ei = e1; e = t - 393216; E = 98304;  noff = 65536; roff = 65537; eoff = 393216; }
    else if (t < 516096) { ei = e2; e = t - 491520; E = 24576;  noff = 81920; roff = 81922; eoff = 491520; }
    else if (t < 522240) { ei = e3; e = t - 516096; E = 6144;   noff = 86016; roff = 86019; eoff = 516096; }
    else                 { ei = e4; e = t - 522240; E = 1536;   noff = 87040; roff = 87044; eoff = 522240; }
    int dst = ld_idx(ei, E + e, is64);
    int pos = rows[roff + dst] + atomicAdd(&cur[noff + dst], 1);
    eids[eoff + pos] = e;
}

// single-level CSR (fallback)
__global__ __launch_bounds__(TPB) void k_csr_count(const void* __restrict__ ei,
                                                   int* __restrict__ cnt, int E,
                                                   const int* __restrict__ flag) {
    int t = blockIdx.x * blockDim.x + threadIdx.x;
    if (t >= E) return;
    int dst = ld_idx(ei, E + t, flag[0]);
    atomicAdd(&cnt[dst], 1);
}

__global__ __launch_bounds__(1024) void k_csr_scan(const int* __restrict__ cnt,
                                                   int* __restrict__ row_ptr) {
    __shared__ int s_part[1024];
    int t = threadIdx.x;
    int base = t * 64;
    int sum = 0;
    for (int i = 0; i < 64; ++i) sum += cnt[base + i];
    s_part[t] = sum;
    __syncthreads();
    for (int off = 1; off < 1024; off <<= 1) {
        int v = (t >= off) ? s_part[t - off] : 0;
        __syncthreads();
        s_part[t] += v;
        __syncthreads();
    }
    int run = (t == 0) ? 0 : s_part[t - 1];
    for (int i = 0; i < 64; ++i) { row_ptr[base + i] = run; run += cnt[base + i]; }
    if (t == 1023) row_ptr[65536] = run;
}

__global__ __launch_bounds__(TPB) void k_csr_fill(const void* __restrict__ ei,
                                                  const int* __restrict__ row_ptr,
                                                  int* __restrict__ cur,
                                                  int* __restrict__ eid, int E,
                                                  const int* __restrict__ flag) {
    int t = blockIdx.x * blockDim.x + threadIdx.x;
    if (t >= E) return;
    int dst = ld_idx(ei, E + t, flag[0]);
    int pos = row_ptr[dst] + atomicAdd(&cur[dst], 1);
    eid[pos] = t;
}

// ---------- c1 gather ----------
__global__ __launch_bounds__(256) void k_gather_c1(const float* __restrict__ x,
                                                   const float* __restrict__ pseudo,
                                                   const void* __restrict__ ei,
                                                   const float* __restrict__ W,
                                                   const float* __restrict__ root,
                                                   const float* __restrict__ bias,
                                                   const int* __restrict__ row_ptr,
                                                   const int* __restrict__ eid,
                                                   float* __restrict__ agg,
                                                   const int* __restrict__ flag) {
    __shared__ float4 s_w[500];
    for (int i = threadIdx.x; i < 500; i += 256)
        s_w[i] = reinterpret_cast<const float4*>(W)[i];
    __syncthreads();
    int t = blockIdx.x * 256 + threadIdx.x;
    int n = t >> 2, cg = t & 3, co0 = cg * 4;
    int is64 = flag[0];
    float xn = x[n];
    float a0 = fmaf(xn, root[co0 + 0], bias[co0 + 0]);
    float a1 = fmaf(xn, root[co0 + 1], bias[co0 + 1]);
    float a2 = fmaf(xn, root[co0 + 2], bias[co0 + 2]);
    float a3 = fmaf(xn, root[co0 + 3], bias[co0 + 3]);
    int rb = row_ptr[n], re = row_ptr[n + 1];
    for (int idx = rb; idx < re; ++idx) {
        int e = eid[idx];
        int src = ld_idx(ei, e, is64);
        float bas[8]; int kidx[8];
        spline_basis(pseudo, e, bas, kidx);
        float xs = x[src];
        float m0 = 0.f, m1 = 0.f, m2 = 0.f, m3 = 0.f;
#pragma unroll
        for (int s = 0; s < 8; ++s) {
            float4 w = s_w[kidx[s] * 4 + cg];
            float bs = bas[s];
            m0 = fmaf(bs, w.x, m0);
            m1 = fmaf(bs, w.y, m1);
            m2 = fmaf(bs, w.z, m2);
            m3 = fmaf(bs, w.w, m3);
        }
        a0 = fmaf(xs, m0, a0);
        a1 = fmaf(xs, m1, a1);
        a2 = fmaf(xs, m2, a2);
        a3 = fmaf(xs, m3, a3);
    }
    float4 v = make_float4(a0, a1, a2, a3);
    *reinterpret_cast<float4*>(&agg[n * 16 + co0]) = v;
}

// ---------- d1 gather ----------
__global__ __launch_bounds__(256) void k_gather_d1(const float* __restrict__ xin,
                                                   const float* __restrict__ pseudo,
                                                   const void* __restrict__ ei,
                                                   const float* __restrict__ W,
                                                   const float* __restrict__ root,
                                                   const float* __restrict__ bias,
                                                   const int* __restrict__ row_ptr,
                                                   const int* __restrict__ eid,
                                                   float* __restrict__ outp,
                                                   const int* __restrict__ flag) {
    __shared__ float s_w[2000];
    for (int i = threadIdx.x; i < 2000; i += 256) s_w[i] = W[i];
    __syncthreads();
    int t = blockIdx.x * 256 + threadIdx.x;
    int n = t >> 2, l = t & 3;
    int is64 = flag[0];
    int rb = row_ptr[n], re = row_ptr[n + 1];
    float acc = 0.f;
    for (int idx = rb + l; idx < re; idx += 4) {
        int e = eid[idx];
        int src = ld_idx(ei, e, is64);
        float bas[8]; int kidx[8];
        spline_basis(pseudo, e, bas, kidx);
        const float4* xs4 = reinterpret_cast<const float4*>(xin + src * 16);
        float4 xv0 = xs4[0], xv1 = xs4[1], xv2 = xs4[2], xv3 = xs4[3];
        float m = 0.f;
#pragma unroll
        for (int s = 0; s < 8; ++s) {
            const float4* wp = reinterpret_cast<const float4*>(s_w + kidx[s] * 16);
            float4 w0 = wp[0], w1 = wp[1], w2 = wp[2], w3 = wp[3];
            float p = 0.f;
            p = fmaf(xv0.x, w0.x, p); p = fmaf(xv0.y, w0.y, p);
            p = fmaf(xv0.z, w0.z, p); p = fmaf(xv0.w, w0.w, p);
            p = fmaf(xv1.x, w1.x, p); p = fmaf(xv1.y, w1.y, p);
            p = fmaf(xv1.z, w1.z, p); p = fmaf(xv1.w, w1.w, p);
            p = fmaf(xv2.x, w2.x, p); p = fmaf(xv2.y, w2.y, p);
            p = fmaf(xv2.z, w2.z, p); p = fmaf(xv2.w, w2.w, p);
            p = fmaf(xv3.x, w3.x, p); p = fmaf(xv3.y, w3.y, p);
            p = fmaf(xv3.z, w3.z, p); p = fmaf(xv3.w, w3.w, p);
            m = fmaf(bas[s], p, m);
        }
        acc += m;
    }
    acc += __shfl_xor(acc, 1);
    acc += __shfl_xor(acc, 2);
    if (l == 0) {
        const float4* xr = reinterpret_cast<const float4*>(xin + n * 16);
        const float4* rr = reinterpret_cast<const float4*>(root);
        float r = bias[0];
#pragma unroll
        for (int q = 0; q < 4; ++q) {
            float4 xv = xr[q], rv = rr[q];
            r = fmaf(xv.x, rv.x, r); r = fmaf(xv.y, rv.y, r);
            r = fmaf(xv.z, rv.z, r); r = fmaf(xv.w, rv.w, r);
        }
        outp[n] = elu_f(r + acc);
    }
}

// ---------- mid-level CSR gather, W slice in LDS (padded rows) ----------
// IROOT: 1 = direct store, root inline (CSPLIT==1);
//        2 = atomicAdd into pre-zeroed agg; cih==0 slice adds root+bias inline.
template <int CIN, int COUT, int CSPLIT, int IROOT>
__global__ __launch_bounds__(256) void k_gW(const float* __restrict__ x,
                                            const float* __restrict__ pseudo,
                                            const void* __restrict__ ei,
                                            const float* __restrict__ W,
                                            const float* __restrict__ root,
                                            const float* __restrict__ bias,
                                            const int* __restrict__ row_ptr,
                                            const int* __restrict__ eid,
                                            float* __restrict__ agg,
                                            const int* __restrict__ flag) {
    constexpr int COG = COUT / 4;
    constexpr int CPT = CIN / CSPLIT;   // = 16 at all call sites
    constexpr int PS = CPT + 1;         // padded row -> bank-group spread
    __shared__ float4 s_w[125 * PS];
    int cg = blockIdx.y, cih = blockIdx.z;
    const float4* W4 = reinterpret_cast<const float4*>(W);
    for (int i = threadIdx.x; i < 125 * CPT; i += 256) {
        int k = i / CPT, ci = i - k * CPT;
        s_w[k * PS + ci] = W4[(k * CIN + cih * CPT + ci) * COG + cg];
    }
    __syncthreads();
    int n = blockIdx.x * 256 + threadIdx.x;
    int is64 = flag[0];
    int co0 = cg * 4;
    float4 acc = make_float4(0.f, 0.f, 0.f, 0.f);
    if (IROOT == 1 || (IROOT == 2 && cih == 0)) {
        acc = reinterpret_cast<const float4*>(bias)[cg];
        const float* xp = x + (size_t)n * CIN;
        const float4* r4 = reinterpret_cast<const float4*>(root);
#pragma unroll 4
        for (int ci = 0; ci < CIN; ++ci) {
            float xv = xp[ci];
            float4 rv = r4[ci * COG + cg];
            acc.x = fmaf(xv, rv.x, acc.x); acc.y = fmaf(xv, rv.y, acc.y);
            acc.z = fmaf(xv, rv.z, acc.z); acc.w = fmaf(xv, rv.w, acc.w);
        }
    }
    int rb = row_ptr[n], re = row_ptr[n + 1];
    for (int idx = rb; idx < re; ++idx) {
        int e = eid[idx];
        int src = ld_idx(ei, e, is64);
        float bas[8]; int kidx[8];
        spline_basis(pseudo, e, bas, kidx);
        float xv[CPT];
        const float* xp = x + (size_t)src * CIN + cih * CPT;
#pragma unroll
        for (int ci = 0; ci < CPT; ++ci) xv[ci] = xp[ci];
#pragma unroll
        for (int s = 0; s < 8; ++s) {
            const float4* wp = s_w + kidx[s] * PS;
            float bs = bas[s];
#pragma unroll
            for (int ci = 0; ci < CPT; ++ci) {
                float bx = bs * xv[ci];
                float4 w = wp[ci];
                acc.x = fmaf(bx, w.x, acc.x); acc.y = fmaf(bx, w.y, acc.y);
                acc.z = fmaf(bx, w.z, acc.z); acc.w = fmaf(bx, w.w, acc.w);
            }
        }
    }
    float* o = agg + (size_t)n * COUT + co0;
    if (IROOT == 1) {
        *reinterpret_cast<float4*>(o) = acc;
    } else {
        atomicAdd(o + 0, acc.x); atomicAdd(o + 1, acc.y);
        atomicAdd(o + 2, acc.z); atomicAdd(o + 3, acc.w);
    }
}

// root transform (fallback path only)
__global__ __launch_bounds__(TPB) void k_root4(const float* __restrict__ x,
                                               const float* __restrict__ root,
                                               const float* __restrict__ bias,
                                               float* __restrict__ out,
                                               int nnode, int cin, int cout) {
    int t = blockIdx.x * blockDim.x + threadIdx.x;
    if (t >= nnode * cout) return;
    int n = t / cout, co = t - n * cout;
    const float4* xr = reinterpret_cast<const float4*>(x + n * cin);
    float a0 = 0.f, a1 = 0.f, a2 = 0.f, a3 = 0.f;
    int q4 = cin >> 2;
    for (int q = 0; q < q4; ++q) {
        float4 xv = xr[q];
        const float* rp = root + (q * 4) * cout + co;
        a0 = fmaf(xv.x, rp[0], a0);
        a1 = fmaf(xv.y, rp[cout], a1);
        a2 = fmaf(xv.z, rp[2 * cout], a2);
        a3 = fmaf(xv.w, rp[3 * cout], a3);
    }
    out[t] = bias[co] + ((a0 + a1) + (a2 + a3));
}

// ---------- fallback atomic msg ----------
template <int CIN, int COUT, int CSPLIT>
__global__ __launch_bounds__(TPB) void k_msg4(const float* __restrict__ x,
                                              const float* __restrict__ pseudo,
                                              const void* __restrict__ ei,
                                              const float* __restrict__ W,
                                              float* __restrict__ agg, int E,
                                              const int* __restrict__ flag) {
    constexpr int COG = COUT / 4;
    constexpr int CPT = CIN / CSPLIT;
    int t = blockIdx.x * blockDim.x + threadIdx.x;
    if (t >= E * COG * CSPLIT) return;
    int is64 = flag[0];
    int cog = t % COG;
    int rest = t / COG;
    int cs = rest % CSPLIT;
    int e = rest / CSPLIT;
    int co0 = cog * 4;
    int src = ld_idx(ei, e, is64);
    int dst = ld_idx(ei, E + e, is64);
    float bas[8]; int kidx[8];
    spline_basis(pseudo, e, bas, kidx);
    int wof[8];
#pragma unroll
    for (int s = 0; s < 8; ++s) wof[s] = kidx[s] * CIN * COUT + co0;
    float a0 = 0.f, a1 = 0.f, a2 = 0.f, a3 = 0.f;
    const float* xp = x + src * CIN + cs * CPT;
    const int cbase = cs * CPT * COUT;
    for (int ci = 0; ci < CPT; ++ci) {
        float xv = xp[ci];
        int off = cbase + ci * COUT;
#pragma unroll
        for (int s = 0; s < 8; ++s) {
            float4 w = *reinterpret_cast<const float4*>(&W[wof[s] + off]);
            float bx = bas[s] * xv;
            a0 = fmaf(bx, w.x, a0);
            a1 = fmaf(bx, w.y, a1);
            a2 = fmaf(bx, w.z, a2);
            a3 = fmaf(bx, w.w, a3);
        }
    }
    float* ap = &agg[dst * COUT + co0];
    atomicAdd(ap + 0, a0);
    atomicAdd(ap + 1, a1);
    atomicAdd(ap + 2, a2);
    atomicAdd(ap + 3, a3);
}

template <int CIN, int COUT>
__global__ __launch_bounds__(TPB) void k_msg_s(const float* __restrict__ x,
                                               const float* __restrict__ pseudo,
                                               const void* __restrict__ ei,
                                               const float* __restrict__ W,
                                               float* __restrict__ agg, int E,
                                               const int* __restrict__ flag) {
    int t = blockIdx.x * blockDim.x + threadIdx.x;
    if (t >= E * COUT) return;
    int is64 = flag[0];
    int e = t / COUT, co = t - e * COUT;
    int src = ld_idx(ei, e, is64);
    int dst = ld_idx(ei, E + e, is64);
    float bas[8]; int kidx[8];
    spline_basis(pseudo, e, bas, kidx);
    float acc = 0.f;
    const float* xp = x + src * CIN;
    for (int ci = 0; ci < CIN; ++ci) {
        float xv = xp[ci];
#pragma unroll
        for (int s = 0; s < 8; ++s)
            acc = fmaf(bas[s] * xv, W[kidx[s] * CIN * COUT + ci * COUT + co], acc);
    }
    atomicAdd(&agg[dst * COUT + co], acc);
}

// c1 fallback (LDS accumulate)
__global__ __launch_bounds__(1024) void k_msg_c1(const float* __restrict__ x,
                                                 const float* __restrict__ pseudo,
                                                 const void* __restrict__ ei,
                                                 const float* __restrict__ W,
                                                 const float* __restrict__ root,
                                                 const float* __restrict__ bias,
                                                 float* __restrict__ agg,
                                                 const int* __restrict__ flag) {
    __shared__ float s_acc[4096 * 4];
    __shared__ float s_w[125 * 4];
    int b = blockIdx.x, cg = blockIdx.y, t = threadIdx.x;
    int co0 = cg * 4;
    int is64 = flag[0];
    if (t < 500) s_w[t] = W[(t >> 2) * 16 + co0 + (t & 3)];
    float r0 = root[co0], r1 = root[co0 + 1], r2 = root[co0 + 2], r3 = root[co0 + 3];
    float b0 = bias[co0], b1 = bias[co0 + 1], b2 = bias[co0 + 2], b3 = bias[co0 + 3];
    for (int n = t; n < 4096; n += 1024) {
        float xv = x[b * 4096 + n];
        s_acc[n * 4 + 0] = fmaf(xv, r0, b0);
        s_acc[n * 4 + 1] = fmaf(xv, r1, b1);
        s_acc[n * 4 + 2] = fmaf(xv, r2, b2);
        s_acc[n * 4 + 3] = fmaf(xv, r3, b3);
    }
    __syncthreads();
    int ebeg = b * 24576;
    for (int k = t; k < 24576; k += 1024) {
        int e = ebeg + k;
        int src = ld_idx(ei, e, is64);
        int dst = ld_idx(ei, 393216 + e, is64);
        float xv = x[src];
        float bas[8]; int kidx[8];
        spline_basis(pseudo, e, bas, kidx);
        float m0 = 0.f, m1 = 0.f, m2 = 0.f, m3 = 0.f;
#pragma unroll
        for (int s = 0; s < 8; ++s) {
            const float* wp = s_w + kidx[s] * 4;
            float bs = bas[s];
            m0 = fmaf(bs, wp[0], m0);
            m1 = fmaf(bs, wp[1], m1);
            m2 = fmaf(bs, wp[2], m2);
            m3 = fmaf(bs, wp[3], m3);
        }
        int dl = (dst - b * 4096) * 4;
        atomicAdd(&s_acc[dl + 0], m0 * xv);
        atomicAdd(&s_acc[dl + 1], m1 * xv);
        atomicAdd(&s_acc[dl + 2], m2 * xv);
        atomicAdd(&s_acc[dl + 3], m3 * xv);
    }
    __syncthreads();
    for (int n = t; n < 4096; n += 1024) {
        float4 v = *reinterpret_cast<float4*>(&s_acc[n * 4]);
        *reinterpret_cast<float4*>(&agg[(b * 4096 + n) * 16 + co0]) = v;
    }
}

// ---------- dual-LDS-staged pool GEMM ----------
template <int F, int ELU>
__global__ __launch_bounds__(256) void k_pool2(const float* __restrict__ in,
                                               const float* __restrict__ P,
                                               float* __restrict__ out,
                                               int nout, int nin) {
    constexpr int FQ = F / 4;
    constexpr int TI = 256 / FQ;
    constexpr int KT = 64;
    constexpr int PS = KT + 4;
    __shared__ float s_p[TI * PS];
    __shared__ float4 s_in[KT * FQ];
    int tid = threadIdx.x;
    int fq = tid % FQ;
    int i = tid / FQ;
    int b = blockIdx.y;
    int gi = blockIdx.x * TI + i;
    int nchunk = nin / gridDim.z;
    int kbeg = blockIdx.z * nchunk;
    const float4* inb4 = reinterpret_cast<const float4*>(in + b * nin * F);
    float4 acc = make_float4(0.f, 0.f, 0.f, 0.f);

    for (int k0 = kbeg; k0 < kbeg + nchunk; k0 += KT) {
        __syncthreads();
        for (int idx = tid; idx < TI * (KT / 4); idx += 256) {
            int r = idx / (KT / 4), c = idx % (KT / 4);
            float4 v = *reinterpret_cast<const float4*>(&P[(blockIdx.x * TI + r) * nin + k0 + c * 4]);
            *reinterpret_cast<float4*>(&s_p[r * PS + c * 4]) = v;
        }
        for (int idx = tid; idx < KT * FQ; idx += 256) {
            float4 v = inb4[(size_t)(k0 + idx / FQ) * FQ + (idx % FQ)];
            if (ELU) {
                v.x = elu_f(v.x); v.y = elu_f(v.y);
                v.z = elu_f(v.z); v.w = elu_f(v.w);
            }
            s_in[idx] = v;
        }
        __syncthreads();
#pragma unroll 4
        for (int j = 0; j < KT; j += 4) {
            float4 pv = *reinterpret_cast<const float4*>(&s_p[i * PS + j]);
            float4 v0 = s_in[(j + 0) * FQ + fq];
            float4 v1 = s_in[(j + 1) * FQ + fq];
            float4 v2 = s_in[(j + 2) * FQ + fq];
            float4 v3 = s_in[(j + 3) * FQ + fq];
            acc.x = fmaf(pv.x, v0.x, acc.x); acc.y = fmaf(pv.x, v0.y, acc.y);
            acc.z = fmaf(pv.x, v0.z, acc.z); acc.w = fmaf(pv.x, v0.w, acc.w);
            acc.x = fmaf(pv.y, v1.x, acc.x); acc.y = fmaf(pv.y, v1.y, acc.y);
            acc.z = fmaf(pv.y, v1.z, acc.z); acc.w = fmaf(pv.y, v1.w, acc.w);
            acc.x = fmaf(pv.z, v2.x, acc.x); acc.y = fmaf(pv.z, v2.y, acc.y);
            acc.z = fmaf(pv.z, v2.z, acc.z); acc.w = fmaf(pv.z, v2.w, acc.w);
            acc.x = fmaf(pv.w, v3.x, acc.x); acc.y = fmaf(pv.w, v3.y, acc.y);
            acc.z = fmaf(pv.w, v3.z, acc.z); acc.w = fmaf(pv.w, v3.w, acc.w);
        }
    }
    float* o = out + ((size_t)b * nout + gi) * F + fq * 4;
    if (gridDim.z > 1) {
        atomicAdd(o + 0, acc.x); atomicAdd(o + 1, acc.y);
        atomicAdd(o + 2, acc.z); atomicAdd(o + 3, acc.w);
    } else {
        *reinterpret_cast<float4*>(o) = acc;
    }
}

__global__ __launch_bounds__(TPB) void k_pool_e(const float* __restrict__ in,
                                                const float* __restrict__ P,
                                                float* __restrict__ out,
                                                int nout, int nin, int F, int elu) {
    int t = blockIdx.x * blockDim.x + threadIdx.x;
    if (t >= 16 * nout * F) return;
    int f = t % F;
    int rest = t / F;
    int i = rest % nout;
    int b = rest / nout;
    const float* ip = in + b * nin * F + f;
    const float* pp = P + i * nin;
    float acc = 0.f;
    if (elu) {
#pragma unroll 4
        for (int j = 0; j < nin; ++j) acc = fmaf(pp[j], elu_f(ip[j * F]), acc);
    } else {
#pragma unroll 4
        for (int j = 0; j < nin; ++j) acc = fmaf(pp[j], ip[j * F], acc);
    }
    out[t] = acc;
}

// ---------- fused bottleneck ----------
__global__ __launch_bounds__(1024) void k_fc_fused2(
        const float* __restrict__ c5agg, const float* __restrict__ Pn1,
        const float* __restrict__ fce1_w, const float* __restrict__ fce1_b,
        const float* __restrict__ fce21_w, const float* __restrict__ fce21_b,
        const float* __restrict__ fce22_w, const float* __restrict__ fce22_b,
        const float* __restrict__ eps,
        const float* __restrict__ fcd3_w, const float* __restrict__ fcd3_b,
        const float* __restrict__ fcd4_w, const float* __restrict__ fcd4_b,
        const float* __restrict__ P1n,
        float* __restrict__ out_mu, float* __restrict__ out_lv,
        float* __restrict__ dec_in) {
    __shared__ float s0[256], s1[256], sz[32], sp[1024];
    int b = blockIdx.x, t = threadIdx.x;
    if (t < 256) {
        const float* ap = c5agg + b * 4096 + t;
        float acc = 0.f;
#pragma unroll
        for (int n = 0; n < 16; ++n) acc = fmaf(Pn1[n], elu_f(ap[n * 256]), acc);
        s0[t] = acc;
    }
    __syncthreads();
    {
        int q = t >> 8, co = t & 255;
        const float* w = fce1_w + co;
        float a = 0.f;
        int c0 = q * 64;
        for (int ci = 0; ci < 64; ci += 8) {
#pragma unroll
            for (int k = 0; k < 8; ++k) a = fmaf(s0[c0 + ci + k], w[(c0 + ci + k) * 256], a);
        }
        sp[t] = a;
    }
    __syncthreads();
    if (t < 256) s1[t] = elu_f(sp[t] + sp[t + 256] + sp[t + 512] + sp[t + 768] + fce1_b[t]);
    __syncthreads();
    if (t < 512) {
        int which = t >> 8, r = t & 255;
        int co = r & 31, q = r >> 5;
        const float* w = (which ? fce22_w : fce21_w) + co;
        float a = 0.f;
        int c0 = q * 32;
#pragma unroll
        for (int k = 0; k < 32; ++k) a = fmaf(s1[c0 + k], w[(c0 + k) * 32], a);
        sp[t] = a;
    }
    __syncthreads();
    if (t < 64) {
        int which = t >> 5, co = t & 31;
        float m = (which ? fce22_b : fce21_b)[co];
        int base = which * 256 + co;
#pragma unroll
        for (int q = 0; q < 8; ++q) m += sp[base + q * 32];
        if (which == 0) { out_mu[b * 32 + co] = m; s0[co] = m; }
        else            { out_lv[b * 32 + co] = m; s0[64 + co] = m; }
    }
    __syncthreads();
    if (t < 32) sz[t] = fmaf(eps[b * 32 + t], expf(0.5f * s0[64 + t]), s0[t]);
    __syncthreads();
    if (t < 256) {
        float d = fcd3_b[t];
#pragma unroll
        for (int ci = 0; ci < 32; ++ci) d = fmaf(sz[ci], fcd3_w[ci * 256 + t], d);
        s0[t] = elu_f(d);
    }
    __syncthreads();
    {
        int q = t >> 8, co = t & 255;
        const float* w = fcd4_w + co;
        float a = 0.f;
        int c0 = q * 64;
        for (int ci = 0; ci < 64; ci += 8) {
#pragma unroll
            for (int k = 0; k < 8; ++k) a = fmaf(s0[c0 + ci + k], w[(c0 + ci + k) * 256], a);
        }
        sp[t] = a;
    }
    __syncthreads();
    if (t < 256) s1[t] = elu_f(sp[t] + sp[t + 256] + sp[t + 512] + sp[t + 768] + fcd4_b[t]);
    __syncthreads();
    {
        float* op = dec_in + b * 4096;
        for (int idx = t; idx < 4096; idx += 1024) {
            int n = idx >> 8, f = idx & 255;
            op[idx] = P1n[n] * s1[f];
        }
    }
}

__global__ __launch_bounds__(TPB) void k_elu_out(const float* __restrict__ in,
                                                 float* __restrict__ out, int n) {
    int t = blockIdx.x * blockDim.x + threadIdx.x;
    if (t < n) out[t] = elu_f(in[t]);
}

extern "C" void kernel_launch(void* const* d_in, const int* in_sizes, int n_in,
                              void* d_out, int out_size, void* d_ws, size_t ws_size,
                              hipStream_t stream) {
    const float* x    = (const float*)d_in[0];
    const float* ea0  = (const float*)d_in[1];
    const float* ea1  = (const float*)d_in[2];
    const float* ea2  = (const float*)d_in[3];
    const float* ea3  = (const float*)d_in[4];
    const float* ea4  = (const float*)d_in[5];
    const float* P01  = (const float*)d_in[6];
    const float* P12  = (const float*)d_in[7];
    const float* P23  = (const float*)d_in[8];
    const float* P34  = (const float*)d_in[9];
    const float* Pn1  = (const float*)d_in[10];
    const float* P1n  = (const float*)d_in[11];
    const float* P43  = (const float*)d_in[12];
    const float* P32  = (const float*)d_in[13];
    const float* P21  = (const float*)d_in[14];
    const float* P10  = (const float*)d_in[15];
    const float* W_c1 = (const float*)d_in[16]; const float* r_c1 = (const float*)d_in[17]; const float* b_c1 = (const float*)d_in[18];
    const float* W_c2 = (const float*)d_in[19]; const float* r_c2 = (const float*)d_in[20]; const float* b_c2 = (const float*)d_in[21];
    const float* W_c3 = (const float*)d_in[22]; const float* r_c3 = (const float*)d_in[23]; const float* b_c3 = (const float*)d_in[24];
    const float* W_c4 = (const float*)d_in[25]; const float* r_c4 = (const float*)d_in[26]; const float* b_c4 = (const float*)d_in[27];
    const float* W_c5 = (const float*)d_in[28]; const float* r_c5 = (const float*)d_in[29]; const float* b_c5 = (const float*)d_in[30];
    const float* W_d5 = (const float*)d_in[31]; const float* r_d5 = (const float*)d_in[32]; const float* b_d5 = (const float*)d_in[33];
    const float* W_d4 = (const float*)d_in[34]; const float* r_d4 = (const float*)d_in[35]; const float* b_d4 = (const float*)d_in[36];
    const float* W_d3 = (const float*)d_in[37]; const float* r_d3 = (const float*)d_in[38]; const float* b_d3 = (const float*)d_in[39];
    const float* W_d2 = (const float*)d_in[40]; const float* r_d2 = (const float*)d_in[41]; const float* b_d2 = (const float*)d_in[42];
    const float* W_d1 = (const float*)d_in[43]; const float* r_d1 = (const float*)d_in[44]; const float* b_d1 = (const float*)d_in[45];
    const float* fce1_w  = (const float*)d_in[46]; const float* fce1_b  = (const float*)d_in[47];
    const float* fce21_w = (const float*)d_in[48]; const float* fce21_b = (const float*)d_in[49];
    const float* fce22_w = (const float*)d_in[50]; const float* fce22_b = (const float*)d_in[51];
    const float* fcd3_w  = (const float*)d_in[52]; const float* fcd3_b  = (const float*)d_in[53];
    const float* fcd4_w  = (const float*)d_in[54]; const float* fcd4_b  = (const float*)d_in[55];
    const float* eps  = (const float*)d_in[56];
    const void* ei0 = d_in[57];
    const void* ei1 = d_in[58];
    const void* ei2 = d_in[59];
    const void* ei3 = d_in[60];
    const void* ei4 = d_in[61];

    const int E0 = 393216, E1 = 98304, E2 = 24576, E3 = 6144, E4 = 1536;
    const int N0 = 65536, N1 = 16384, N2 = 4096, N3 = 1024, N4 = 256;

    float* sm   = (float*)d_ws;
    float* bufA = sm + 13824;
    float* bufB = bufA + 1048576;
    int*  flag  = (int*)(bufB + 262144);
    int*  ibase = flag + 64;
    int* cur  = ibase;
    int* rows = cur + 87296;
    int* eids = rows + 87301;
    int* bsum = eids + 523776;
    const size_t WS_ALL = (size_t)(13824 + 1048576 + 262144 + 64 + 87296 + 87301 + 523776 + 512) * 4;
    int* o_row = ibase;
    int* o_cur = o_row + 65537;
    int* o_eid = o_cur + 65536;
    const size_t WS_OLD = (size_t)(13824 + 1048576 + 262144 + 64 + 524352) * 4;
    const bool bigA = ws_size >= WS_ALL;
    const bool big0 = ws_size >= WS_OLD;

    const int ROFF[5] = {0, 65537, 81922, 86019, 87044};
    const int EOFF[5] = {0, 393216, 491520, 516096, 522240};

    float* out = (float*)d_out;
    float* out_mu = out + 65536;
    float* out_lv = out + 66048;

    auto g = [](int n) { return dim3((unsigned)CDIV(n, TPB)); };

    k_detect<<<1, 64, 0, stream>>>((const int*)ei0, flag);

    if (bigA) {
        k_zero_i<<<g(87296), TPB, 0, stream>>>(cur, 87296);
        k_csr_count5<<<g(523776), TPB, 0, stream>>>(ei0, ei1, ei2, ei3, ei4, cur, flag);
        k_scan_a<<<341, 256, 0, stream>>>(cur, rows, bsum);
        k_scan_b<<<5, 256, 0, stream>>>(bsum, rows);
        k_scan_c<<<341, 256, 0, stream>>>(bsum, rows);
        k_zero_i<<<g(87296), TPB, 0, stream>>>(cur, 87296);
        k_csr_fill5<<<g(523776), TPB, 0, stream>>>(ei0, ei1, ei2, ei3, ei4, rows, cur, eids, flag);

        // ---------------- encoder ----------------
        k_gather_c1<<<1024, 256, 0, stream>>>(x, ea0, ei0, W_c1, r_c1, b_c1,
                                              rows + ROFF[0], eids + EOFF[0], bufA, flag);
        k_zero<<<g(262144), TPB, 0, stream>>>(bufB, 262144);
        k_pool2<16, 1><<<dim3(16, 16, 4), 256, 0, stream>>>(bufA, P01, bufB, 1024, 4096);

        k_gW<16, 32, 1, 1><<<dim3(64, 8, 1), 256, 0, stream>>>(bufB, ea1, ei1, W_c2, r_c2, b_c2,
                                                               rows + ROFF[1], eids + EOFF[1], bufA, flag);
        k_zero<<<g(131072), TPB, 0, stream>>>(bufB, 131072);
        k_pool2<32, 1><<<dim3(8, 16, 2), 256, 0, stream>>>(bufA, P12, bufB, 256, 1024);

        k_zero<<<g(262144), TPB, 0, stream>>>(bufA, 262144);
        k_gW<32, 64, 2, 2><<<dim3(16, 16, 2), 256, 0, stream>>>(bufB, ea2, ei2, W_c3, r_c3, b_c3,
                                                                rows + ROFF[2], eids + EOFF[2], bufA, flag);
        k_zero<<<g(65536), TPB, 0, stream>>>(bufB, 65536);
        k_pool2<64, 1><<<dim3(4, 16, 2), 256, 0, stream>>>(bufA, P23, bufB, 64, 256);

        k_zero<<<g(131072), TPB, 0, stream>>>(bufA, 131072);
        k_gW<64, 128, 4, 2><<<dim3(4, 32, 4), 256, 0, stream>>>(bufB, ea3, ei3, W_c4, r_c4, b_c4,
                                                                rows + ROFF[3], eids + EOFF[3], bufA, flag);
        k_pool_e<<<g(16 * 16 * 128), TPB, 0, stream>>>(bufA, P34, bufB, 16, 64, 128, 1);

        k_zero<<<g(65536), TPB, 0, stream>>>(bufA, 65536);
        k_gW<128, 256, 8, 2><<<dim3(1, 64, 8), 256, 0, stream>>>(bufB, ea4, ei4, W_c5, r_c5, b_c5,
                                                                 rows + ROFF[4], eids + EOFF[4], bufA, flag);

        k_fc_fused2<<<16, 1024, 0, stream>>>(bufA, Pn1,
                                             fce1_w, fce1_b, fce21_w, fce21_b, fce22_w, fce22_b,
                                             eps, fcd3_w, fcd3_b, fcd4_w, fcd4_b, P1n,
                                             out_mu, out_lv, bufA);

        // ---------------- decoder ----------------
        k_zero<<<g(32768), TPB, 0, stream>>>(bufB, 32768);
        k_gW<256, 128, 16, 2><<<dim3(1, 32, 16), 256, 0, stream>>>(bufA, ea4, ei4, W_d5, r_d5, b_d5,
                                                                   rows + ROFF[4], eids + EOFF[4], bufB, flag);
        k_pool_e<<<g(16 * 64 * 128), TPB, 0, stream>>>(bufB, P43, bufA, 64, 16, 128, 1);

        k_zero<<<g(65536), TPB, 0, stream>>>(bufB, 65536);
        k_gW<128, 64, 8, 2><<<dim3(4, 16, 8), 256, 0, stream>>>(bufA, ea3, ei3, W_d4, r_d4, b_d4,
                                                                rows + ROFF[3], eids + EOFF[3], bufB, flag);
        k_pool2<64, 1><<<dim3(16, 16, 1), 256, 0, stream>>>(bufB, P32, bufA, 256, 64);

        k_zero<<<g(131072), TPB, 0, stream>>>(bufB, 131072);
        k_gW<64, 32, 4, 2><<<dim3(16, 8, 4), 256, 0, stream>>>(bufA, ea2, ei2, W_d3, r_d3, b_d3,
                                                               rows + ROFF[2], eids + EOFF[2], bufB, flag);
        k_pool2<32, 1><<<dim3(32, 16, 1), 256, 0, stream>>>(bufB, P21, bufA, 1024, 256);

        k_zero<<<g(262144), TPB, 0, stream>>>(bufB, 262144);
        k_gW<32, 16, 2, 2><<<dim3(64, 4, 2), 256, 0, stream>>>(bufA, ea1, ei1, W_d2, r_d2, b_d2,
                                                               rows + ROFF[1], eids + EOFF[1], bufB, flag);
        k_pool2<16, 1><<<dim3(64, 16, 1), 256, 0, stream>>>(bufB, P10, bufA, 4096, 1024);

        k_gather_d1<<<1024, 256, 0, stream>>>(bufA, ea0, ei0, W_d1, r_d1, b_d1,
                                              rows + ROFF[0], eids + EOFF[0], out, flag);
        return;
    }

    // ================= fallback paths =================
    if (big0) {
        k_zero_i<<<g(65536), TPB, 0, stream>>>(o_cur, 65536);
        k_csr_count<<<g(E0), TPB, 0, stream>>>(ei0, o_cur, E0, flag);
        k_csr_scan<<<1, 1024, 0, stream>>>(o_cur, o_row);
        k_zero_i<<<g(65536), TPB, 0, stream>>>(o_cur, 65536);
        k_csr_fill<<<g(E0), TPB, 0, stream>>>(ei0, o_row, o_cur, o_eid, E0, flag);
        k_gather_c1<<<1024, 256, 0, stream>>>(x, ea0, ei0, W_c1, r_c1, b_c1,
                                              o_row, o_eid, bufA, flag);
    } else {
        k_msg_c1<<<dim3(16, 4), 1024, 0, stream>>>(x, ea0, ei0, W_c1, r_c1, b_c1, bufA, flag);
    }
    k_zero<<<g(262144), TPB, 0, stream>>>(bufB, 262144);
    k_pool2<16, 1><<<dim3(16, 16, 4), 256, 0, stream>>>(bufA, P01, bufB, 1024, 4096);

    k_root4<<<g(N1 * 32), TPB, 0, stream>>>(bufB, r_c2, b_c2, bufA, N1, 16, 32);
    k_msg4<16, 32, 1><<<g(E1 * 8), TPB, 0, stream>>>(bufB, ea1, ei1, W_c2, bufA, E1, flag);
    k_zero<<<g(131072), TPB, 0, stream>>>(bufB, 131072);
    k_pool2<32, 1><<<dim3(8, 16, 2), 256, 0, stream>>>(bufA, P12, bufB, 256, 1024);

    k_root4<<<g(N2 * 64), TPB, 0, stream>>>(bufB, r_c3, b_c3, bufA, N2, 32, 64);
    k_msg4<32, 64, 1><<<g(E2 * 16), TPB, 0, stream>>>(bufB, ea2, ei2, W_c3, bufA, E2, flag);
    k_zero<<<g(65536), TPB, 0, stream>>>(bufB, 65536);
    k_pool2<64, 1><<<dim3(4, 16, 2), 256, 0, stream>>>(bufA, P23, bufB, 64, 256);

    k_root4<<<g(N3 * 128), TPB, 0, stream>>>(bufB, r_c4, b_c4, bufA, N3, 64, 128);
    k_msg4<64, 128, 1><<<g(E3 * 32), TPB, 0, stream>>>(bufB, ea3, ei3, W_c4, bufA, E3, flag);
    k_pool_e<<<g(16 * 16 * 128), TPB, 0, stream>>>(bufA, P34, bufB, 16, 64, 128, 1);

    k_root4<<<g(N4 * 256), TPB, 0, stream>>>(bufB, r_c5, b_c5, bufA, N4, 128, 256);
    k_msg4<128, 256, 2><<<g(E4 * 128), TPB, 0, stream>>>(bufB, ea4, ei4, W_c5, bufA, E4, flag);

    k_fc_fused2<<<16, 1024, 0, stream>>>(bufA, Pn1,
                                         fce1_w, fce1_b, fce21_w, fce21_b, fce22_w, fce22_b,
                                         eps, fcd3_w, fcd3_b, fcd4_w, fcd4_b, P1n,
                                         out_mu, out_lv, bufA);

    k_root4<<<g(N4 * 128), TPB, 0, stream>>>(bufA, r_d5, b_d5, bufB, N4, 256, 128);
    k_msg4<256, 128, 4><<<g(E4 * 128), TPB, 0, stream>>>(bufA, ea4, ei4, W_d5, bufB, E4, flag);
    k_pool_e<<<g(16 * 64 * 128), TPB, 0, stream>>>(bufB, P43, bufA, 64, 16, 128, 1);

    k_root4<<<g(N3 * 64), TPB, 0, stream>>>(bufA, r_d4, b_d4, bufB, N3, 128, 64);
    k_msg4<128, 64, 2><<<g(E3 * 32), TPB, 0, stream>>>(bufA, ea3, ei3, W_d4, bufB, E3, flag);
    k_pool2<64, 1><<<dim3(16, 16, 1), 256, 0, stream>>>(bufB, P32, bufA, 256, 64);

    k_root4<<<g(N2 * 32), TPB, 0, stream>>>(bufA, r_d3, b_d3, bufB, N2, 64, 32);
    k_msg4<64, 32, 1><<<g(E2 * 8), TPB, 0, stream>>>(bufA, ea2, ei2, W_d3, bufB, E2, flag);
    k_pool2<32, 1><<<dim3(32, 16, 1), 256, 0, stream>>>(bufB, P21, bufA, 1024, 256);

    k_root4<<<g(N1 * 16), TPB, 0, stream>>>(bufA, r_d2, b_d2, bufB, N1, 32, 16);
    k_msg4<32, 16, 1><<<g(E1 * 4), TPB, 0, stream>>>(bufA, ea1, ei1, W_d2, bufB, E1, flag);
    k_pool2<16, 1><<<dim3(64, 16, 1), 256, 0, stream>>>(bufB, P10, bufA, 4096, 1024);

    if (big0) {
        k_gather_d1<<<1024, 256, 0, stream>>>(bufA, ea0, ei0, W_d1, r_d1, b_d1,
                                              o_row, o_eid, out, flag);
    } else {
        k_root4<<<g(N0 * 1), TPB, 0, stream>>>(bufA, r_d1, b_d1, bufB, N0, 16, 1);
        k_msg_s<16, 1><<<g(E0), TPB, 0, stream>>>(bufA, ea0, ei0, W_d1, bufB, E0, flag);
        k_elu_out<<<g(N0), TPB, 0, stream>>>(bufB, out, 65536);
    }
}

// Round 16
// 866.260 us; speedup vs baseline: 2.3409x; 1.1134x over previous
//
#include <hip/hip_runtime.h>
#include <hip/hip_bf16.h>

#define TPB 256
#define CDIV(a,b) (((a)+(b)-1)/(b))

__device__ __forceinline__ float elu_f(float v) {
    return v > 0.f ? v : expm1f(v);
}

__device__ __forceinline__ int ld_idx(const void* __restrict__ ei, int pos, int is64) {
    if (is64) return (int)((const long long*)ei)[pos];
    return ((const int*)ei)[pos];
}

__device__ __forceinline__ void spline_basis(const float* __restrict__ pseudo, int e,
                                             float bas[8], int kidx[8]) {
    float f[3]; int lo[3];
#pragma unroll
    for (int d = 0; d < 3; ++d) {
        float v = pseudo[e * 3 + d] * 4.f;
        float l = floorf(v);
        l = fminf(fmaxf(l, 0.f), 3.f);
        f[d] = v - l;
        lo[d] = (int)l;
    }
#pragma unroll
    for (int s = 0; s < 8; ++s) {
        int b0 = s & 1, b1 = (s >> 1) & 1, b2 = (s >> 2) & 1;
        bas[s] = (b0 ? f[0] : 1.f - f[0]) * (b1 ? f[1] : 1.f - f[1]) * (b2 ? f[2] : 1.f - f[2]);
        kidx[s] = (lo[0] + b0) + 5 * (lo[1] + b1) + 25 * (lo[2] + b2);
    }
}

__global__ void k_detect(const int* __restrict__ ei0_as_i32, int* __restrict__ flag) {
    if (threadIdx.x == 0 && blockIdx.x == 0) {
        int zeros = 0;
        for (int k = 0; k < 128; ++k)
            if (ei0_as_i32[2 * k + 1] == 0) zeros++;
        flag[0] = (zeros >= 120) ? 1 : 0;
    }
}

__global__ __launch_bounds__(TPB) void k_zero(float* __restrict__ p, int n) {
    int t = blockIdx.x * blockDim.x + threadIdx.x;
    if (t < n) p[t] = 0.f;
}

__global__ __launch_bounds__(TPB) void k_zero_i(int* __restrict__ p, int n) {
    int t = blockIdx.x * blockDim.x + threadIdx.x;
    if (t < n) p[t] = 0;
}

// =========== multi-level CSR (levels 0..4) ===========
__global__ __launch_bounds__(TPB) void k_csr_count5(const void* e0, const void* e1,
                                                    const void* e2, const void* e3,
                                                    const void* e4, int* __restrict__ cnt,
                                                    const int* __restrict__ flag) {
    int t = blockIdx.x * blockDim.x + threadIdx.x;
    if (t >= 523776) return;
    int is64 = flag[0];
    const void* ei; int e, E, noff;
    if (t < 393216)      { ei = e0; e = t;          E = 393216; noff = 0; }
    else if (t < 491520) { ei = e1; e = t - 393216; E = 98304;  noff = 65536; }
    else if (t < 516096) { ei = e2; e = t - 491520; E = 24576;  noff = 81920; }
    else if (t < 522240) { ei = e3; e = t - 516096; E = 6144;   noff = 86016; }
    else                 { ei = e4; e = t - 522240; E = 1536;   noff = 87040; }
    int dst = ld_idx(ei, E + e, is64);
    atomicAdd(&cnt[noff + dst], 1);
}

__device__ __forceinline__ void lvl_of_block(int b, int& l, int& lb) {
    if (b < 256)      { l = 0; lb = b; }
    else if (b < 320) { l = 1; lb = b - 256; }
    else if (b < 336) { l = 2; lb = b - 320; }
    else if (b < 340) { l = 3; lb = b - 336; }
    else              { l = 4; lb = b - 340; }
}

__global__ __launch_bounds__(256) void k_scan_a(const int* __restrict__ cnt,
                                                int* __restrict__ rows,
                                                int* __restrict__ bsum) {
    const int NOFF[5] = {0, 65536, 81920, 86016, 87040};
    const int ROFF[5] = {0, 65537, 81922, 86019, 87044};
    __shared__ int s[256];
    int l, lb; lvl_of_block(blockIdx.x, l, lb);
    int t = threadIdx.x;
    int i = lb * 256 + t;
    int v = cnt[NOFF[l] + i];
    s[t] = v;
    __syncthreads();
    for (int off = 1; off < 256; off <<= 1) {
        int u = (t >= off) ? s[t - off] : 0;
        __syncthreads();
        s[t] += u;
        __syncthreads();
    }
    rows[ROFF[l] + i] = s[t] - v;
    if (t == 255) bsum[blockIdx.x] = s[255];
}

__global__ __launch_bounds__(256) void k_scan_b(int* __restrict__ bsum,
                                                int* __restrict__ rows) {
    const int NB[5]    = {256, 64, 16, 4, 1};
    const int BOFF[5]  = {0, 256, 320, 336, 340};
    const int ROFF[5]  = {0, 65537, 81922, 86019, 87044};
    const int NODES[5] = {65536, 16384, 4096, 1024, 256};
    __shared__ int s[256];
    int l = blockIdx.x, t = threadIdx.x;
    int nb = NB[l];
    int v = (t < nb) ? bsum[BOFF[l] + t] : 0;
    s[t] = v;
    __syncthreads();
    for (int off = 1; off < 256; off <<= 1) {
        int u = (t >= off) ? s[t - off] : 0;
        __syncthreads();
        s[t] += u;
        __syncthreads();
    }
    if (t < nb) bsum[BOFF[l] + t] = s[t] - v;
    if (t == 0) rows[ROFF[l] + NODES[l]] = s[255];
}

__global__ __launch_bounds__(256) void k_scan_c(const int* __restrict__ bsum,
                                                int* __restrict__ rows) {
    const int ROFF[5] = {0, 65537, 81922, 86019, 87044};
    int l, lb; lvl_of_block(blockIdx.x, l, lb);
    rows[ROFF[l] + lb * 256 + threadIdx.x] += bsum[blockIdx.x];
}

__global__ __launch_bounds__(TPB) void k_csr_fill5(const void* e0, const void* e1,
                                                   const void* e2, const void* e3,
                                                   const void* e4,
                                                   const int* __restrict__ rows,
                                                   int* __restrict__ cur,
                                                   int* __restrict__ eids,
                                                   const int* __restrict__ flag) {
    int t = blockIdx.x * blockDim.x + threadIdx.x;
    if (t >= 523776) return;
    int is64 = flag[0];
    const void* ei; int e, E, noff, roff, eoff;
    if (t < 393216)      { ei = e0; e = t;          E = 393216; noff = 0;     roff = 0;     eoff = 0; }
    else if (t < 491520) { ei = e1; e = t - 393216; E = 98304;  noff = 65536; roff = 65537; eoff = 393216; }
    else if (t < 516096) { ei = e2; e = t - 491520; E = 24576;  noff = 81920; roff = 81922; eoff = 491520; }
    else if (t < 522240) { ei = e3; e = t - 516096; E = 6144;   noff = 86016; roff = 86019; eoff = 516096; }
    else                 { ei = e4; e = t - 522240; E = 1536;   noff = 87040; roff = 87044; eoff = 522240; }
    int dst = ld_idx(ei, E + e, is64);
    int pos = rows[roff + dst] + atomicAdd(&cur[noff + dst], 1);
    eids[eoff + pos] = e;
}

// single-level CSR (fallback)
__global__ __launch_bounds__(TPB) void k_csr_count(const void* __restrict__ ei,
                                                   int* __restrict__ cnt, int E,
                                                   const int* __restrict__ flag) {
    int t = blockIdx.x * blockDim.x + threadIdx.x;
    if (t >= E) return;
    int dst = ld_idx(ei, E + t, flag[0]);
    atomicAdd(&cnt[dst], 1);
}

__global__ __launch_bounds__(1024) void k_csr_scan(const int* __restrict__ cnt,
                                                   int* __restrict__ row_ptr) {
    __shared__ int s_part[1024];
    int t = threadIdx.x;
    int base = t * 64;
    int sum = 0;
    for (int i = 0; i < 64; ++i) sum += cnt[base + i];
    s_part[t] = sum;
    __syncthreads();
    for (int off = 1; off < 1024; off <<= 1) {
        int v = (t >= off) ? s_part[t - off] : 0;
        __syncthreads();
        s_part[t] += v;
        __syncthreads();
    }
    int run = (t == 0) ? 0 : s_part[t - 1];
    for (int i = 0; i < 64; ++i) { row_ptr[base + i] = run; run += cnt[base + i]; }
    if (t == 1023) row_ptr[65536] = run;
}

__global__ __launch_bounds__(TPB) void k_csr_fill(const void* __restrict__ ei,
                                                  const int* __restrict__ row_ptr,
                                                  int* __restrict__ cur,
                                                  int* __restrict__ eid, int E,
                                                  const int* __restrict__ flag) {
    int t = blockIdx.x * blockDim.x + threadIdx.x;
    if (t >= E) return;
    int dst = ld_idx(ei, E + t, flag[0]);
    int pos = row_ptr[dst] + atomicAdd(&cur[dst], 1);
    eid[pos] = t;
}

// ---------- c1 gather ----------
__global__ __launch_bounds__(256) void k_gather_c1(const float* __restrict__ x,
                                                   const float* __restrict__ pseudo,
                                                   const void* __restrict__ ei,
                                                   const float* __restrict__ W,
                                                   const float* __restrict__ root,
                                                   const float* __restrict__ bias,
                                                   const int* __restrict__ row_ptr,
                                                   const int* __restrict__ eid,
                                                   float* __restrict__ agg,
                                                   const int* __restrict__ flag) {
    __shared__ float4 s_w[500];
    for (int i = threadIdx.x; i < 500; i += 256)
        s_w[i] = reinterpret_cast<const float4*>(W)[i];
    __syncthreads();
    int t = blockIdx.x * 256 + threadIdx.x;
    int n = t >> 2, cg = t & 3, co0 = cg * 4;
    int is64 = flag[0];
    float xn = x[n];
    float a0 = fmaf(xn, root[co0 + 0], bias[co0 + 0]);
    float a1 = fmaf(xn, root[co0 + 1], bias[co0 + 1]);
    float a2 = fmaf(xn, root[co0 + 2], bias[co0 + 2]);
    float a3 = fmaf(xn, root[co0 + 3], bias[co0 + 3]);
    int rb = row_ptr[n], re = row_ptr[n + 1];
    for (int idx = rb; idx < re; ++idx) {
        int e = eid[idx];
        int src = ld_idx(ei, e, is64);
        float bas[8]; int kidx[8];
        spline_basis(pseudo, e, bas, kidx);
        float xs = x[src];
        float m0 = 0.f, m1 = 0.f, m2 = 0.f, m3 = 0.f;
#pragma unroll
        for (int s = 0; s < 8; ++s) {
            float4 w = s_w[kidx[s] * 4 + cg];
            float bs = bas[s];
            m0 = fmaf(bs, w.x, m0);
            m1 = fmaf(bs, w.y, m1);
            m2 = fmaf(bs, w.z, m2);
            m3 = fmaf(bs, w.w, m3);
        }
        a0 = fmaf(xs, m0, a0);
        a1 = fmaf(xs, m1, a1);
        a2 = fmaf(xs, m2, a2);
        a3 = fmaf(xs, m3, a3);
    }
    float4 v = make_float4(a0, a1, a2, a3);
    *reinterpret_cast<float4*>(&agg[n * 16 + co0]) = v;
}

// ---------- d1 gather ----------
__global__ __launch_bounds__(256) void k_gather_d1(const float* __restrict__ xin,
                                                   const float* __restrict__ pseudo,
                                                   const void* __restrict__ ei,
                                                   const float* __restrict__ W,
                                                   const float* __restrict__ root,
                                                   const float* __restrict__ bias,
                                                   const int* __restrict__ row_ptr,
                                                   const int* __restrict__ eid,
                                                   float* __restrict__ outp,
                                                   const int* __restrict__ flag) {
    __shared__ float s_w[2000];
    for (int i = threadIdx.x; i < 2000; i += 256) s_w[i] = W[i];
    __syncthreads();
    int t = blockIdx.x * 256 + threadIdx.x;
    int n = t >> 2, l = t & 3;
    int is64 = flag[0];
    int rb = row_ptr[n], re = row_ptr[n + 1];
    float acc = 0.f;
    for (int idx = rb + l; idx < re; idx += 4) {
        int e = eid[idx];
        int src = ld_idx(ei, e, is64);
        float bas[8]; int kidx[8];
        spline_basis(pseudo, e, bas, kidx);
        const float4* xs4 = reinterpret_cast<const float4*>(xin + src * 16);
        float4 xv0 = xs4[0], xv1 = xs4[1], xv2 = xs4[2], xv3 = xs4[3];
        float m = 0.f;
#pragma unroll
        for (int s = 0; s < 8; ++s) {
            const float4* wp = reinterpret_cast<const float4*>(s_w + kidx[s] * 16);
            float4 w0 = wp[0], w1 = wp[1], w2 = wp[2], w3 = wp[3];
            float p = 0.f;
            p = fmaf(xv0.x, w0.x, p); p = fmaf(xv0.y, w0.y, p);
            p = fmaf(xv0.z, w0.z, p); p = fmaf(xv0.w, w0.w, p);
            p = fmaf(xv1.x, w1.x, p); p = fmaf(xv1.y, w1.y, p);
            p = fmaf(xv1.z, w1.z, p); p = fmaf(xv1.w, w1.w, p);
            p = fmaf(xv2.x, w2.x, p); p = fmaf(xv2.y, w2.y, p);
            p = fmaf(xv2.z, w2.z, p); p = fmaf(xv2.w, w2.w, p);
            p = fmaf(xv3.x, w3.x, p); p = fmaf(xv3.y, w3.y, p);
            p = fmaf(xv3.z, w3.z, p); p = fmaf(xv3.w, w3.w, p);
            m = fmaf(bas[s], p, m);
        }
        acc += m;
    }
    acc += __shfl_xor(acc, 1);
    acc += __shfl_xor(acc, 2);
    if (l == 0) {
        const float4* xr = reinterpret_cast<const float4*>(xin + n * 16);
        const float4* rr = reinterpret_cast<const float4*>(root);
        float r = bias[0];
#pragma unroll
        for (int q = 0; q < 4; ++q) {
            float4 xv = xr[q], rv = rr[q];
            r = fmaf(xv.x, rv.x, r); r = fmaf(xv.y, rv.y, r);
            r = fmaf(xv.z, rv.z, r); r = fmaf(xv.w, rv.w, r);
        }
        outp[n] = elu_f(r + acc);
    }
}

// ---------- mid-level CSR gather v2: 64 nodes x 4 edge-lanes per block ----------
// W slice (cg,cih) in LDS with padded rows; 4x the blocks of v1 for occupancy.
// IROOT: 1 = direct store (CSPLIT==1, root inline); 2 = atomic into pre-zeroed agg,
//        cih==0 adds root+bias (split across the 4 lanes, merged by the reduce).
template <int CIN, int COUT, int CSPLIT, int IROOT>
__global__ __launch_bounds__(256) void k_gW2(const float* __restrict__ x,
                                             const float* __restrict__ pseudo,
                                             const void* __restrict__ ei,
                                             const float* __restrict__ W,
                                             const float* __restrict__ root,
                                             const float* __restrict__ bias,
                                             const int* __restrict__ row_ptr,
                                             const int* __restrict__ eid,
                                             float* __restrict__ agg,
                                             const int* __restrict__ flag) {
    constexpr int COG = COUT / 4;
    constexpr int CPT = CIN / CSPLIT;   // = 16 at all call sites
    constexpr int PS = CPT + 1;         // padded row -> bank-group spread
    __shared__ float4 s_w[125 * PS];
    int cg = blockIdx.y, cih = blockIdx.z;
    const float4* W4 = reinterpret_cast<const float4*>(W);
    for (int i = threadIdx.x; i < 125 * CPT; i += 256) {
        int k = i / CPT, ci = i - k * CPT;
        s_w[k * PS + ci] = W4[(k * CIN + cih * CPT + ci) * COG + cg];
    }
    __syncthreads();
    int nl = threadIdx.x >> 2, l = threadIdx.x & 3;
    int n = blockIdx.x * 64 + nl;
    int is64 = flag[0];
    int co0 = cg * 4;
    float4 acc = make_float4(0.f, 0.f, 0.f, 0.f);
    if (IROOT == 1 || (IROOT == 2 && cih == 0)) {
        // root/bias split over the 4 lanes; merged by the quad reduce below.
        if (l == 0) acc = reinterpret_cast<const float4*>(bias)[cg];
        constexpr int CQ = CIN / 4;
        const float* xp = x + (size_t)n * CIN + l * CQ;
        const float4* r4 = reinterpret_cast<const float4*>(root) + (size_t)(l * CQ) * COG + cg;
#pragma unroll 4
        for (int ci = 0; ci < CQ; ++ci) {
            float xv = xp[ci];
            float4 rv = r4[ci * COG];
            acc.x = fmaf(xv, rv.x, acc.x); acc.y = fmaf(xv, rv.y, acc.y);
            acc.z = fmaf(xv, rv.z, acc.z); acc.w = fmaf(xv, rv.w, acc.w);
        }
    }
    int rb = row_ptr[n], re = row_ptr[n + 1];
    for (int idx = rb + l; idx < re; idx += 4) {
        int e = eid[idx];
        int src = ld_idx(ei, e, is64);
        float bas[8]; int kidx[8];
        spline_basis(pseudo, e, bas, kidx);
        float xv[CPT];
        const float* xp = x + (size_t)src * CIN + cih * CPT;
#pragma unroll
        for (int ci = 0; ci < CPT; ++ci) xv[ci] = xp[ci];
#pragma unroll
        for (int s = 0; s < 8; ++s) {
            const float4* wp = s_w + kidx[s] * PS;
            float bs = bas[s];
#pragma unroll
            for (int ci = 0; ci < CPT; ++ci) {
                float bx = bs * xv[ci];
                float4 w = wp[ci];
                acc.x = fmaf(bx, w.x, acc.x); acc.y = fmaf(bx, w.y, acc.y);
                acc.z = fmaf(bx, w.z, acc.z); acc.w = fmaf(bx, w.w, acc.w);
            }
        }
    }
    // quad reduce (lanes n*4+0..3 are contiguous in the wave)
    acc.x += __shfl_xor(acc.x, 1); acc.y += __shfl_xor(acc.y, 1);
    acc.z += __shfl_xor(acc.z, 1); acc.w += __shfl_xor(acc.w, 1);
    acc.x += __shfl_xor(acc.x, 2); acc.y += __shfl_xor(acc.y, 2);
    acc.z += __shfl_xor(acc.z, 2); acc.w += __shfl_xor(acc.w, 2);
    if (l == 0) {
        float* o = agg + (size_t)n * COUT + co0;
        if (IROOT == 1) {
            *reinterpret_cast<float4*>(o) = acc;
        } else {
            atomicAdd(o + 0, acc.x); atomicAdd(o + 1, acc.y);
            atomicAdd(o + 2, acc.z); atomicAdd(o + 3, acc.w);
        }
    }
}

// root transform (fallback path only)
__global__ __launch_bounds__(TPB) void k_root4(const float* __restrict__ x,
                                               const float* __restrict__ root,
                                               const float* __restrict__ bias,
                                               float* __restrict__ out,
                                               int nnode, int cin, int cout) {
    int t = blockIdx.x * blockDim.x + threadIdx.x;
    if (t >= nnode * cout) return;
    int n = t / cout, co = t - n * cout;
    const float4* xr = reinterpret_cast<const float4*>(x + n * cin);
    float a0 = 0.f, a1 = 0.f, a2 = 0.f, a3 = 0.f;
    int q4 = cin >> 2;
    for (int q = 0; q < q4; ++q) {
        float4 xv = xr[q];
        const float* rp = root + (q * 4) * cout + co;
        a0 = fmaf(xv.x, rp[0], a0);
        a1 = fmaf(xv.y, rp[cout], a1);
        a2 = fmaf(xv.z, rp[2 * cout], a2);
        a3 = fmaf(xv.w, rp[3 * cout], a3);
    }
    out[t] = bias[co] + ((a0 + a1) + (a2 + a3));
}

// ---------- fallback atomic msg ----------
template <int CIN, int COUT, int CSPLIT>
__global__ __launch_bounds__(TPB) void k_msg4(const float* __restrict__ x,
                                              const float* __restrict__ pseudo,
                                              const void* __restrict__ ei,
                                              const float* __restrict__ W,
                                              float* __restrict__ agg, int E,
                                              const int* __restrict__ flag) {
    constexpr int COG = COUT / 4;
    constexpr int CPT = CIN / CSPLIT;
    int t = blockIdx.x * blockDim.x + threadIdx.x;
    if (t >= E * COG * CSPLIT) return;
    int is64 = flag[0];
    int cog = t % COG;
    int rest = t / COG;
    int cs = rest % CSPLIT;
    int e = rest / CSPLIT;
    int co0 = cog * 4;
    int src = ld_idx(ei, e, is64);
    int dst = ld_idx(ei, E + e, is64);
    float bas[8]; int kidx[8];
    spline_basis(pseudo, e, bas, kidx);
    int wof[8];
#pragma unroll
    for (int s = 0; s < 8; ++s) wof[s] = kidx[s] * CIN * COUT + co0;
    float a0 = 0.f, a1 = 0.f, a2 = 0.f, a3 = 0.f;
    const float* xp = x + src * CIN + cs * CPT;
    const int cbase = cs * CPT * COUT;
    for (int ci = 0; ci < CPT; ++ci) {
        float xv = xp[ci];
        int off = cbase + ci * COUT;
#pragma unroll
        for (int s = 0; s < 8; ++s) {
            float4 w = *reinterpret_cast<const float4*>(&W[wof[s] + off]);
            float bx = bas[s] * xv;
            a0 = fmaf(bx, w.x, a0);
            a1 = fmaf(bx, w.y, a1);
            a2 = fmaf(bx, w.z, a2);
            a3 = fmaf(bx, w.w, a3);
        }
    }
    float* ap = &agg[dst * COUT + co0];
    atomicAdd(ap + 0, a0);
    atomicAdd(ap + 1, a1);
    atomicAdd(ap + 2, a2);
    atomicAdd(ap + 3, a3);
}

template <int CIN, int COUT>
__global__ __launch_bounds__(TPB) void k_msg_s(const float* __restrict__ x,
                                               const float* __restrict__ pseudo,
                                               const void* __restrict__ ei,
                                               const float* __restrict__ W,
                                               float* __restrict__ agg, int E,
                                               const int* __restrict__ flag) {
    int t = blockIdx.x * blockDim.x + threadIdx.x;
    if (t >= E * COUT) return;
    int is64 = flag[0];
    int e = t / COUT, co = t - e * COUT;
    int src = ld_idx(ei, e, is64);
    int dst = ld_idx(ei, E + e, is64);
    float bas[8]; int kidx[8];
    spline_basis(pseudo, e, bas, kidx);
    float acc = 0.f;
    const float* xp = x + src * CIN;
    for (int ci = 0; ci < CIN; ++ci) {
        float xv = xp[ci];
#pragma unroll
        for (int s = 0; s < 8; ++s)
            acc = fmaf(bas[s] * xv, W[kidx[s] * CIN * COUT + ci * COUT + co], acc);
    }
    atomicAdd(&agg[dst * COUT + co], acc);
}

// c1 fallback (LDS accumulate)
__global__ __launch_bounds__(1024) void k_msg_c1(const float* __restrict__ x,
                                                 const float* __restrict__ pseudo,
                                                 const void* __restrict__ ei,
                                                 const float* __restrict__ W,
                                                 const float* __restrict__ root,
                                                 const float* __restrict__ bias,
                                                 float* __restrict__ agg,
                                                 const int* __restrict__ flag) {
    __shared__ float s_acc[4096 * 4];
    __shared__ float s_w[125 * 4];
    int b = blockIdx.x, cg = blockIdx.y, t = threadIdx.x;
    int co0 = cg * 4;
    int is64 = flag[0];
    if (t < 500) s_w[t] = W[(t >> 2) * 16 + co0 + (t & 3)];
    float r0 = root[co0], r1 = root[co0 + 1], r2 = root[co0 + 2], r3 = root[co0 + 3];
    float b0 = bias[co0], b1 = bias[co0 + 1], b2 = bias[co0 + 2], b3 = bias[co0 + 3];
    for (int n = t; n < 4096; n += 1024) {
        float xv = x[b * 4096 + n];
        s_acc[n * 4 + 0] = fmaf(xv, r0, b0);
        s_acc[n * 4 + 1] = fmaf(xv, r1, b1);
        s_acc[n * 4 + 2] = fmaf(xv, r2, b2);
        s_acc[n * 4 + 3] = fmaf(xv, r3, b3);
    }
    __syncthreads();
    int ebeg = b * 24576;
    for (int k = t; k < 24576; k += 1024) {
        int e = ebeg + k;
        int src = ld_idx(ei, e, is64);
        int dst = ld_idx(ei, 393216 + e, is64);
        float xv = x[src];
        float bas[8]; int kidx[8];
        spline_basis(pseudo, e, bas, kidx);
        float m0 = 0.f, m1 = 0.f, m2 = 0.f, m3 = 0.f;
#pragma unroll
        for (int s = 0; s < 8; ++s) {
            const float* wp = s_w + kidx[s] * 4;
            float bs = bas[s];
            m0 = fmaf(bs, wp[0], m0);
            m1 = fmaf(bs, wp[1], m1);
            m2 = fmaf(bs, wp[2], m2);
            m3 = fmaf(bs, wp[3], m3);
        }
        int dl = (dst - b * 4096) * 4;
        atomicAdd(&s_acc[dl + 0], m0 * xv);
        atomicAdd(&s_acc[dl + 1], m1 * xv);
        atomicAdd(&s_acc[dl + 2], m2 * xv);
        atomicAdd(&s_acc[dl + 3], m3 * xv);
    }
    __syncthreads();
    for (int n = t; n < 4096; n += 1024) {
        float4 v = *reinterpret_cast<float4*>(&s_acc[n * 4]);
        *reinterpret_cast<float4*>(&agg[(b * 4096 + n) * 16 + co0]) = v;
    }
}

// ---------- dual-LDS-staged pool GEMM ----------
template <int F, int ELU>
__global__ __launch_bounds__(256) void k_pool2(const float* __restrict__ in,
                                               const float* __restrict__ P,
                                               float* __restrict__ out,
                                               int nout, int nin) {
    constexpr int FQ = F / 4;
    constexpr int TI = 256 / FQ;
    constexpr int KT = 64;
    constexpr int PS = KT + 4;
    __shared__ float s_p[TI * PS];
    __shared__ float4 s_in[KT * FQ];
    int tid = threadIdx.x;
    int fq = tid % FQ;
    int i = tid / FQ;
    int b = blockIdx.y;
    int gi = blockIdx.x * TI + i;
    int nchunk = nin / gridDim.z;
    int kbeg = blockIdx.z * nchunk;
    const float4* inb4 = reinterpret_cast<const float4*>(in + b * nin * F);
    float4 acc = make_float4(0.f, 0.f, 0.f, 0.f);

    for (int k0 = kbeg; k0 < kbeg + nchunk; k0 += KT) {
        __syncthreads();
        for (int idx = tid; idx < TI * (KT / 4); idx += 256) {
            int r = idx / (KT / 4), c = idx % (KT / 4);
            float4 v = *reinterpret_cast<const float4*>(&P[(blockIdx.x * TI + r) * nin + k0 + c * 4]);
            *reinterpret_cast<float4*>(&s_p[r * PS + c * 4]) = v;
        }
        for (int idx = tid; idx < KT * FQ; idx += 256) {
            float4 v = inb4[(size_t)(k0 + idx / FQ) * FQ + (idx % FQ)];
            if (ELU) {
                v.x = elu_f(v.x); v.y = elu_f(v.y);
                v.z = elu_f(v.z); v.w = elu_f(v.w);
            }
            s_in[idx] = v;
        }
        __syncthreads();
#pragma unroll 4
        for (int j = 0; j < KT; j += 4) {
            float4 pv = *reinterpret_cast<const float4*>(&s_p[i * PS + j]);
            float4 v0 = s_in[(j + 0) * FQ + fq];
            float4 v1 = s_in[(j + 1) * FQ + fq];
            float4 v2 = s_in[(j + 2) * FQ + fq];
            float4 v3 = s_in[(j + 3) * FQ + fq];
            acc.x = fmaf(pv.x, v0.x, acc.x); acc.y = fmaf(pv.x, v0.y, acc.y);
            acc.z = fmaf(pv.x, v0.z, acc.z); acc.w = fmaf(pv.x, v0.w, acc.w);
            acc.x = fmaf(pv.y, v1.x, acc.x); acc.y = fmaf(pv.y, v1.y, acc.y);
            acc.z = fmaf(pv.y, v1.z, acc.z); acc.w = fmaf(pv.y, v1.w, acc.w);
            acc.x = fmaf(pv.z, v2.x, acc.x); acc.y = fmaf(pv.z, v2.y, acc.y);
            acc.z = fmaf(pv.z, v2.z, acc.z); acc.w = fmaf(pv.z, v2.w, acc.w);
            acc.x = fmaf(pv.w, v3.x, acc.x); acc.y = fmaf(pv.w, v3.y, acc.y);
            acc.z = fmaf(pv.w, v3.z, acc.z); acc.w = fmaf(pv.w, v3.w, acc.w);
        }
    }
    float* o = out + ((size_t)b * nout + gi) * F + fq * 4;
    if (gridDim.z > 1) {
        atomicAdd(o + 0, acc.x); atomicAdd(o + 1, acc.y);
        atomicAdd(o + 2, acc.z); atomicAdd(o + 3, acc.w);
    } else {
        *reinterpret_cast<float4*>(o) = acc;
    }
}

__global__ __launch_bounds__(TPB) void k_pool_e(const float* __restrict__ in,
                                                const float* __restrict__ P,
                                                float* __restrict__ out,
                                                int nout, int nin, int F, int elu) {
    int t = blockIdx.x * blockDim.x + threadIdx.x;
    if (t >= 16 * nout * F) return;
    int f = t % F;
    int rest = t / F;
    int i = rest % nout;
    int b = rest / nout;
    const float* ip = in + b * nin * F + f;
    const float* pp = P + i * nin;
    float acc = 0.f;
    if (elu) {
#pragma unroll 4
        for (int j = 0; j < nin; ++j) acc = fmaf(pp[j], elu_f(ip[j * F]), acc);
    } else {
#pragma unroll 4
        for (int j = 0; j < nin; ++j) acc = fmaf(pp[j], ip[j * F], acc);
    }
    out[t] = acc;
}

// ---------- fused bottleneck ----------
__global__ __launch_bounds__(1024) void k_fc_fused2(
        const float* __restrict__ c5agg, const float* __restrict__ Pn1,
        const float* __restrict__ fce1_w, const float* __restrict__ fce1_b,
        const float* __restrict__ fce21_w, const float* __restrict__ fce21_b,
        const float* __restrict__ fce22_w, const float* __restrict__ fce22_b,
        const float* __restrict__ eps,
        const float* __restrict__ fcd3_w, const float* __restrict__ fcd3_b,
        const float* __restrict__ fcd4_w, const float* __restrict__ fcd4_b,
        const float* __restrict__ P1n,
        float* __restrict__ out_mu, float* __restrict__ out_lv,
        float* __restrict__ dec_in) {
    __shared__ float s0[256], s1[256], sz[32], sp[1024];
    int b = blockIdx.x, t = threadIdx.x;
    if (t < 256) {
        const float* ap = c5agg + b * 4096 + t;
        float acc = 0.f;
#pragma unroll
        for (int n = 0; n < 16; ++n) acc = fmaf(Pn1[n], elu_f(ap[n * 256]), acc);
        s0[t] = acc;
    }
    __syncthreads();
    {
        int q = t >> 8, co = t & 255;
        const float* w = fce1_w + co;
        float a = 0.f;
        int c0 = q * 64;
        for (int ci = 0; ci < 64; ci += 8) {
#pragma unroll
            for (int k = 0; k < 8; ++k) a = fmaf(s0[c0 + ci + k], w[(c0 + ci + k) * 256], a);
        }
        sp[t] = a;
    }
    __syncthreads();
    if (t < 256) s1[t] = elu_f(sp[t] + sp[t + 256] + sp[t + 512] + sp[t + 768] + fce1_b[t]);
    __syncthreads();
    if (t < 512) {
        int which = t >> 8, r = t & 255;
        int co = r & 31, q = r >> 5;
        const float* w = (which ? fce22_w : fce21_w) + co;
        float a = 0.f;
        int c0 = q * 32;
#pragma unroll
        for (int k = 0; k < 32; ++k) a = fmaf(s1[c0 + k], w[(c0 + k) * 32], a);
        sp[t] = a;
    }
    __syncthreads();
    if (t < 64) {
        int which = t >> 5, co = t & 31;
        float m = (which ? fce22_b : fce21_b)[co];
        int base = which * 256 + co;
#pragma unroll
        for (int q = 0; q < 8; ++q) m += sp[base + q * 32];
        if (which == 0) { out_mu[b * 32 + co] = m; s0[co] = m; }
        else            { out_lv[b * 32 + co] = m; s0[64 + co] = m; }
    }
    __syncthreads();
    if (t < 32) sz[t] = fmaf(eps[b * 32 + t], expf(0.5f * s0[64 + t]), s0[t]);
    __syncthreads();
    if (t < 256) {
        float d = fcd3_b[t];
#pragma unroll
        for (int ci = 0; ci < 32; ++ci) d = fmaf(sz[ci], fcd3_w[ci * 256 + t], d);
        s0[t] = elu_f(d);
    }
    __syncthreads();
    {
        int q = t >> 8, co = t & 255;
        const float* w = fcd4_w + co;
        float a = 0.f;
        int c0 = q * 64;
        for (int ci = 0; ci < 64; ci += 8) {
#pragma unroll
            for (int k = 0; k < 8; ++k) a = fmaf(s0[c0 + ci + k], w[(c0 + ci + k) * 256], a);
        }
        sp[t] = a;
    }
    __syncthreads();
    if (t < 256) s1[t] = elu_f(sp[t] + sp[t + 256] + sp[t + 512] + sp[t + 768] + fcd4_b[t]);
    __syncthreads();
    {
        float* op = dec_in + b * 4096;
        for (int idx = t; idx < 4096; idx += 1024) {
            int n = idx >> 8, f = idx & 255;
            op[idx] = P1n[n] * s1[f];
        }
    }
}

__global__ __launch_bounds__(TPB) void k_elu_out(const float* __restrict__ in,
                                                 float* __restrict__ out, int n) {
    int t = blockIdx.x * blockDim.x + threadIdx.x;
    if (t < n) out[t] = elu_f(in[t]);
}

extern "C" void kernel_launch(void* const* d_in, const int* in_sizes, int n_in,
                              void* d_out, int out_size, void* d_ws, size_t ws_size,
                              hipStream_t stream) {
    const float* x    = (const float*)d_in[0];
    const float* ea0  = (const float*)d_in[1];
    const float* ea1  = (const float*)d_in[2];
    const float* ea2  = (const float*)d_in[3];
    const float* ea3  = (const float*)d_in[4];
    const float* ea4  = (const float*)d_in[5];
    const float* P01  = (const float*)d_in[6];
    const float* P12  = (const float*)d_in[7];
    const float* P23  = (const float*)d_in[8];
    const float* P34  = (const float*)d_in[9];
    const float* Pn1  = (const float*)d_in[10];
    const float* P1n  = (const float*)d_in[11];
    const float* P43  = (const float*)d_in[12];
    const float* P32  = (const float*)d_in[13];
    const float* P21  = (const float*)d_in[14];
    const float* P10  = (const float*)d_in[15];
    const float* W_c1 = (const float*)d_in[16]; const float* r_c1 = (const float*)d_in[17]; const float* b_c1 = (const float*)d_in[18];
    const float* W_c2 = (const float*)d_in[19]; const float* r_c2 = (const float*)d_in[20]; const float* b_c2 = (const float*)d_in[21];
    const float* W_c3 = (const float*)d_in[22]; const float* r_c3 = (const float*)d_in[23]; const float* b_c3 = (const float*)d_in[24];
    const float* W_c4 = (const float*)d_in[25]; const float* r_c4 = (const float*)d_in[26]; const float* b_c4 = (const float*)d_in[27];
    const float* W_c5 = (const float*)d_in[28]; const float* r_c5 = (const float*)d_in[29]; const float* b_c5 = (const float*)d_in[30];
    const float* W_d5 = (const float*)d_in[31]; const float* r_d5 = (const float*)d_in[32]; const float* b_d5 = (const float*)d_in[33];
    const float* W_d4 = (const float*)d_in[34]; const float* r_d4 = (const float*)d_in[35]; const float* b_d4 = (const float*)d_in[36];
    const float* W_d3 = (const float*)d_in[37]; const float* r_d3 = (const float*)d_in[38]; const float* b_d3 = (const float*)d_in[39];
    const float* W_d2 = (const float*)d_in[40]; const float* r_d2 = (const float*)d_in[41]; const float* b_d2 = (const float*)d_in[42];
    const float* W_d1 = (const float*)d_in[43]; const float* r_d1 = (const float*)d_in[44]; const float* b_d1 = (const float*)d_in[45];
    const float* fce1_w  = (const float*)d_in[46]; const float* fce1_b  = (const float*)d_in[47];
    const float* fce21_w = (const float*)d_in[48]; const float* fce21_b = (const float*)d_in[49];
    const float* fce22_w = (const float*)d_in[50]; const float* fce22_b = (const float*)d_in[51];
    const float* fcd3_w  = (const float*)d_in[52]; const float* fcd3_b  = (const float*)d_in[53];
    const float* fcd4_w  = (const float*)d_in[54]; const float* fcd4_b  = (const float*)d_in[55];
    const float* eps  = (const float*)d_in[56];
    const void* ei0 = d_in[57];
    const void* ei1 = d_in[58];
    const void* ei2 = d_in[59];
    const void* ei3 = d_in[60];
    const void* ei4 = d_in[61];

    const int E0 = 393216, E1 = 98304, E2 = 24576, E3 = 6144, E4 = 1536;
    const int N0 = 65536, N1 = 16384, N2 = 4096, N3 = 1024, N4 = 256;

    float* sm   = (float*)d_ws;
    float* bufA = sm + 13824;
    float* bufB = bufA + 1048576;
    int*  flag  = (int*)(bufB + 262144);
    int*  ibase = flag + 64;
    int* cur  = ibase;
    int* rows = cur + 87296;
    int* eids = rows + 87301;
    int* bsum = eids + 523776;
    const size_t WS_ALL = (size_t)(13824 + 1048576 + 262144 + 64 + 87296 + 87301 + 523776 + 512) * 4;
    int* o_row = ibase;
    int* o_cur = o_row + 65537;
    int* o_eid = o_cur + 65536;
    const size_t WS_OLD = (size_t)(13824 + 1048576 + 262144 + 64 + 524352) * 4;
    const bool bigA = ws_size >= WS_ALL;
    const bool big0 = ws_size >= WS_OLD;

    const int ROFF[5] = {0, 65537, 81922, 86019, 87044};
    const int EOFF[5] = {0, 393216, 491520, 516096, 522240};

    float* out = (float*)d_out;
    float* out_mu = out + 65536;
    float* out_lv = out + 66048;

    auto g = [](int n) { return dim3((unsigned)CDIV(n, TPB)); };

    k_detect<<<1, 64, 0, stream>>>((const int*)ei0, flag);

    if (bigA) {
        k_zero_i<<<g(87296), TPB, 0, stream>>>(cur, 87296);
        k_csr_count5<<<g(523776), TPB, 0, stream>>>(ei0, ei1, ei2, ei3, ei4, cur, flag);
        k_scan_a<<<341, 256, 0, stream>>>(cur, rows, bsum);
        k_scan_b<<<5, 256, 0, stream>>>(bsum, rows);
        k_scan_c<<<341, 256, 0, stream>>>(bsum, rows);
        k_zero_i<<<g(87296), TPB, 0, stream>>>(cur, 87296);
        k_csr_fill5<<<g(523776), TPB, 0, stream>>>(ei0, ei1, ei2, ei3, ei4, rows, cur, eids, flag);

        // ---------------- encoder ----------------
        k_gather_c1<<<1024, 256, 0, stream>>>(x, ea0, ei0, W_c1, r_c1, b_c1,
                                              rows + ROFF[0], eids + EOFF[0], bufA, flag);
        k_zero<<<g(262144), TPB, 0, stream>>>(bufB, 262144);
        k_pool2<16, 1><<<dim3(16, 16, 4), 256, 0, stream>>>(bufA, P01, bufB, 1024, 4096);

        k_gW2<16, 32, 1, 1><<<dim3(256, 8, 1), 256, 0, stream>>>(bufB, ea1, ei1, W_c2, r_c2, b_c2,
                                                                 rows + ROFF[1], eids + EOFF[1], bufA, flag);
        k_zero<<<g(131072), TPB, 0, stream>>>(bufB, 131072);
        k_pool2<32, 1><<<dim3(8, 16, 2), 256, 0, stream>>>(bufA, P12, bufB, 256, 1024);

        k_zero<<<g(262144), TPB, 0, stream>>>(bufA, 262144);
        k_gW2<32, 64, 2, 2><<<dim3(64, 16, 2), 256, 0, stream>>>(bufB, ea2, ei2, W_c3, r_c3, b_c3,
                                                                 rows + ROFF[2], eids + EOFF[2], bufA, flag);
        k_zero<<<g(65536), TPB, 0, stream>>>(bufB, 65536);
        k_pool2<64, 1><<<dim3(4, 16, 2), 256, 0, stream>>>(bufA, P23, bufB, 64, 256);

        k_zero<<<g(131072), TPB, 0, stream>>>(bufA, 131072);
        k_gW2<64, 128, 4, 2><<<dim3(16, 32, 4), 256, 0, stream>>>(bufB, ea3, ei3, W_c4, r_c4, b_c4,
                                                                  rows + ROFF[3], eids + EOFF[3], bufA, flag);
        k_pool_e<<<g(16 * 16 * 128), TPB, 0, stream>>>(bufA, P34, bufB, 16, 64, 128, 1);

        k_zero<<<g(65536), TPB, 0, stream>>>(bufA, 65536);
        k_gW2<128, 256, 8, 2><<<dim3(4, 64, 8), 256, 0, stream>>>(bufB, ea4, ei4, W_c5, r_c5, b_c5,
                                                                  rows + ROFF[4], eids + EOFF[4], bufA, flag);

        k_fc_fused2<<<16, 1024, 0, stream>>>(bufA, Pn1,
                                             fce1_w, fce1_b, fce21_w, fce21_b, fce22_w, fce22_b,
                                             eps, fcd3_w, fcd3_b, fcd4_w, fcd4_b, P1n,
                                             out_mu, out_lv, bufA);

        // ---------------- decoder ----------------
        k_zero<<<g(32768), TPB, 0, stream>>>(bufB, 32768);
        k_gW2<256, 128, 16, 2><<<dim3(4, 32, 16), 256, 0, stream>>>(bufA, ea4, ei4, W_d5, r_d5, b_d5,
                                                                    rows + ROFF[4], eids + EOFF[4], bufB, flag);
        k_pool_e<<<g(16 * 64 * 128), TPB, 0, stream>>>(bufB, P43, bufA, 64, 16, 128, 1);

        k_zero<<<g(65536), TPB, 0, stream>>>(bufB, 65536);
        k_gW2<128, 64, 8, 2><<<dim3(16, 16, 8), 256, 0, stream>>>(bufA, ea3, ei3, W_d4, r_d4, b_d4,
                                                                  rows + ROFF[3], eids + EOFF[3], bufB, flag);
        k_pool2<64, 1><<<dim3(16, 16, 1), 256, 0, stream>>>(bufB, P32, bufA, 256, 64);

        k_zero<<<g(131072), TPB, 0, stream>>>(bufB, 131072);
        k_gW2<64, 32, 4, 2><<<dim3(64, 8, 4), 256, 0, stream>>>(bufA, ea2, ei2, W_d3, r_d3, b_d3,
                                                                rows + ROFF[2], eids + EOFF[2], bufB, flag);
        k_pool2<32, 1><<<dim3(32, 16, 1), 256, 0, stream>>>(bufB, P21, bufA, 1024, 256);

        k_zero<<<g(262144), TPB, 0, stream>>>(bufB, 262144);
        k_gW2<32, 16, 2, 2><<<dim3(256, 4, 2), 256, 0, stream>>>(bufA, ea1, ei1, W_d2, r_d2, b_d2,
                                                                 rows + ROFF[1], eids + EOFF[1], bufB, flag);
        k_pool2<16, 1><<<dim3(64, 16, 1), 256, 0, stream>>>(bufB, P10, bufA, 4096, 1024);

        k_gather_d1<<<1024, 256, 0, stream>>>(bufA, ea0, ei0, W_d1, r_d1, b_d1,
                                              rows + ROFF[0], eids + EOFF[0], out, flag);
        return;
    }

    // ================= fallback paths =================
    if (big0) {
        k_zero_i<<<g(65536), TPB, 0, stream>>>(o_cur, 65536);
        k_csr_count<<<g(E0), TPB, 0, stream>>>(ei0, o_cur, E0, flag);
        k_csr_scan<<<1, 1024, 0, stream>>>(o_cur, o_row);
        k_zero_i<<<g(65536), TPB, 0, stream>>>(o_cur, 65536);
        k_csr_fill<<<g(E0), TPB, 0, stream>>>(ei0, o_row, o_cur, o_eid, E0, flag);
        k_gather_c1<<<1024, 256, 0, stream>>>(x, ea0, ei0, W_c1, r_c1, b_c1,
                                              o_row, o_eid, bufA, flag);
    } else {
        k_msg_c1<<<dim3(16, 4), 1024, 0, stream>>>(x, ea0, ei0, W_c1, r_c1, b_c1, bufA, flag);
    }
    k_zero<<<g(262144), TPB, 0, stream>>>(bufB, 262144);
    k_pool2<16, 1><<<dim3(16, 16, 4), 256, 0, stream>>>(bufA, P01, bufB, 1024, 4096);

    k_root4<<<g(N1 * 32), TPB, 0, stream>>>(bufB, r_c2, b_c2, bufA, N1, 16, 32);
    k_msg4<16, 32, 1><<<g(E1 * 8), TPB, 0, stream>>>(bufB, ea1, ei1, W_c2, bufA, E1, flag);
    k_zero<<<g(131072), TPB, 0, stream>>>(bufB, 131072);
    k_pool2<32, 1><<<dim3(8, 16, 2), 256, 0, stream>>>(bufA, P12, bufB, 256, 1024);

    k_root4<<<g(N2 * 64), TPB, 0, stream>>>(bufB, r_c3, b_c3, bufA, N2, 32, 64);
    k_msg4<32, 64, 1><<<g(E2 * 16), TPB, 0, stream>>>(bufB, ea2, ei2, W_c3, bufA, E2, flag);
    k_zero<<<g(65536), TPB, 0, stream>>>(bufB, 65536);
    k_pool2<64, 1><<<dim3(4, 16, 2), 256, 0, stream>>>(bufA, P23, bufB, 64, 256);

    k_root4<<<g(N3 * 128), TPB, 0, stream>>>(bufB, r_c4, b_c4, bufA, N3, 64, 128);
    k_msg4<64, 128, 1><<<g(E3 * 32), TPB, 0, stream>>>(bufB, ea3, ei3, W_c4, bufA, E3, flag);
    k_pool_e<<<g(16 * 16 * 128), TPB, 0, stream>>>(bufA, P34, bufB, 16, 64, 128, 1);

    k_root4<<<g(N4 * 256), TPB, 0, stream>>>(bufB, r_c5, b_c5, bufA, N4, 128, 256);
    k_msg4<128, 256, 2><<<g(E4 * 128), TPB, 0, stream>>>(bufB, ea4, ei4, W_c5, bufA, E4, flag);

    k_fc_fused2<<<16, 1024, 0, stream>>>(bufA, Pn1,
                                         fce1_w, fce1_b, fce21_w, fce21_b, fce22_w, fce22_b,
                                         eps, fcd3_w, fcd3_b, fcd4_w, fcd4_b, P1n,
                                         out_mu, out_lv, bufA);

    k_root4<<<g(N4 * 128), TPB, 0, stream>>>(bufA, r_d5, b_d5, bufB, N4, 256, 128);
    k_msg4<256, 128, 4><<<g(E4 * 128), TPB, 0, stream>>>(bufA, ea4, ei4, W_d5, bufB, E4, flag);
    k_pool_e<<<g(16 * 64 * 128), TPB, 0, stream>>>(bufB, P43, bufA, 64, 16, 128, 1);

    k_root4<<<g(N3 * 64), TPB, 0, stream>>>(bufA, r_d4, b_d4, bufB, N3, 128, 64);
    k_msg4<128, 64, 2><<<g(E3 * 32), TPB, 0, stream>>>(bufA, ea3, ei3, W_d4, bufB, E3, flag);
    k_pool2<64, 1><<<dim3(16, 16, 1), 256, 0, stream>>>(bufB, P32, bufA, 256, 64);

    k_root4<<<g(N2 * 32), TPB, 0, stream>>>(bufA, r_d3, b_d3, bufB, N2, 64, 32);
    k_msg4<64, 32, 1><<<g(E2 * 8), TPB, 0, stream>>>(bufA, ea2, ei2, W_d3, bufB, E2, flag);
    k_pool2<32, 1><<<dim3(32, 16, 1), 256, 0, stream>>>(bufB, P21, bufA, 1024, 256);

    k_root4<<<g(N1 * 16), TPB, 0, stream>>>(bufA, r_d2, b_d2, bufB, N1, 32, 16);
    k_msg4<32, 16, 1><<<g(E1 * 4), TPB, 0, stream>>>(bufA, ea1, ei1, W_d2, bufB, E1, flag);
    k_pool2<16, 1><<<dim3(64, 16, 1), 256, 0, stream>>>(bufB, P10, bufA, 4096, 1024);

    if (big0) {
        k_gather_d1<<<1024, 256, 0, stream>>>(bufA, ea0, ei0, W_d1, r_d1, b_d1,
                                              o_row, o_eid, out, flag);
    } else {
        k_root4<<<g(N0 * 1), TPB, 0, stream>>>(bufA, r_d1, b_d1, bufB, N0, 16, 1);
        k_msg_s<16, 1><<<g(E0), TPB, 0, stream>>>(bufA, ea0, ei0, W_d1, bufB, E0, flag);
        k_elu_out<<<g(N0), TPB, 0, stream>>>(bufB, out, 65536);
    }
}